// Round 1
// baseline (4139.066 us; speedup 1.0000x reference)
//
#include <hip/hip_runtime.h>

#define M_  4
#define B_  2
#define T_  1024
#define D_  512
#define V_  128
#define L_  4
#define H_  8
#define FF_ 2048
#define DK_ 64
#define BT_ (B_*T_)
#define EPS_ 1e-5f

// ---------------- embedding: h[m,b,t,:] = tok[m, x[b,t], :] + pos[m, t, :] ----------------
__global__ __launch_bounds__(128)
void k_embed(const int* __restrict__ x, const float* __restrict__ tok,
             const float* __restrict__ pos, float* __restrict__ h)
{
  const int t = blockIdx.x, b = blockIdx.y, m = blockIdx.z;
  const int d = threadIdx.x * 4;
  const int xv = x[b*T_ + t];
  const float4 tv = *(const float4*)&tok[((size_t)m*V_ + xv)*D_ + d];
  const float4 pv = *(const float4*)&pos[((size_t)m*1024 + t)*D_ + d];
  float4 r;
  r.x = tv.x + pv.x; r.y = tv.y + pv.y; r.z = tv.z + pv.z; r.w = tv.w + pv.w;
  *(float4*)&h[(((size_t)m*B_ + b)*T_ + t)*D_ + d] = r;
}

// ---------------- layernorm over D=512; one block per row of [M*B*T, D] ----------------
__global__ __launch_bounds__(256)
void k_ln(const float* __restrict__ x, const float* __restrict__ w,
          const float* __restrict__ bb, float* __restrict__ y)
{
  const int row = blockIdx.x;
  const int m = row / BT_;
  const int tid = threadIdx.x;
  const float2 v = *(const float2*)&x[(size_t)row*D_ + tid*2];
  float s  = v.x + v.y;
  float s2 = v.x*v.x + v.y*v.y;
  #pragma unroll
  for (int off = 1; off < 64; off <<= 1) {
    s  += __shfl_xor(s, off);
    s2 += __shfl_xor(s2, off);
  }
  __shared__ float ls[4], ls2[4];
  if ((tid & 63) == 0) { ls[tid>>6] = s; ls2[tid>>6] = s2; }
  __syncthreads();
  s  = ls[0]+ls[1]+ls[2]+ls[3];
  s2 = ls2[0]+ls2[1]+ls2[2]+ls2[3];
  const float mu   = s * (1.0f/D_);
  const float var  = s2 * (1.0f/D_) - mu*mu;
  const float rstd = rsqrtf(var + EPS_);
  const float2 wv = *(const float2*)&w[m*D_ + tid*2];
  const float2 bv = *(const float2*)&bb[m*D_ + tid*2];
  float2 o;
  o.x = (v.x - mu)*rstd*wv.x + bv.x;
  o.y = (v.y - mu)*rstd*wv.y + bv.y;
  *(float2*)&y[(size_t)row*D_ + tid*2] = o;
}

// ---------------- batched GEMM: C[m,r,c] = sum_k A[m,r,k]*W[m,c,k] + bias[m,c] ----------------
// 64x64 tile, BK=32, 256 threads, 4x4 per-thread microtile. LDS k-major (reads conflict-free).
template<int ACT, int RES, int HEADOUT>
__global__ __launch_bounds__(256, 4)
void k_gemm(const float* __restrict__ A, const float* __restrict__ W,
            const float* __restrict__ bias, const float* resid,
            float* C, int RR, int NN, int KK)
{
  const int m  = blockIdx.z;
  const int r0 = blockIdx.x * 64;
  const int c0 = blockIdx.y * 64;
  const float* Am = A + (size_t)m*RR*KK;
  const float* Wm = W + (size_t)m*NN*KK;

  __shared__ float As[32][64];
  __shared__ float Ws[32][64];

  const int tid = threadIdx.x;
  const int ty = tid >> 4, tx = tid & 15;
  const int lr  = tid >> 2;          // 0..63 staging row
  const int lk4 = (tid & 3) * 4;     // 0,4,8,12

  float acc[4][4] = {};

  const float* ap = &Am[(size_t)(r0 + lr)*KK + lk4];
  const float* wp = &Wm[(size_t)(c0 + lr)*KK + lk4];

  for (int k0 = 0; k0 < KK; k0 += 32) {
    const float4 a0 = *(const float4*)(ap + k0);
    const float4 a1 = *(const float4*)(ap + k0 + 16);
    const float4 w0 = *(const float4*)(wp + k0);
    const float4 w1 = *(const float4*)(wp + k0 + 16);
    __syncthreads();
    As[lk4+0][lr]=a0.x; As[lk4+1][lr]=a0.y; As[lk4+2][lr]=a0.z; As[lk4+3][lr]=a0.w;
    As[lk4+16][lr]=a1.x; As[lk4+17][lr]=a1.y; As[lk4+18][lr]=a1.z; As[lk4+19][lr]=a1.w;
    Ws[lk4+0][lr]=w0.x; Ws[lk4+1][lr]=w0.y; Ws[lk4+2][lr]=w0.z; Ws[lk4+3][lr]=w0.w;
    Ws[lk4+16][lr]=w1.x; Ws[lk4+17][lr]=w1.y; Ws[lk4+18][lr]=w1.z; Ws[lk4+19][lr]=w1.w;
    __syncthreads();
    #pragma unroll
    for (int k = 0; k < 32; ++k) {
      const float4 av = *(const float4*)&As[k][ty*4];
      const float4 wv = *(const float4*)&Ws[k][tx*4];
      const float ar[4] = {av.x, av.y, av.z, av.w};
      const float wr[4] = {wv.x, wv.y, wv.z, wv.w};
      #pragma unroll
      for (int i = 0; i < 4; ++i)
        #pragma unroll
        for (int j = 0; j < 4; ++j)
          acc[i][j] = fmaf(ar[i], wr[j], acc[i][j]);
    }
  }

  const float4 bv = *(const float4*)&bias[(size_t)m*NN + c0 + tx*4];
  const float br[4] = {bv.x, bv.y, bv.z, bv.w};
  #pragma unroll
  for (int i = 0; i < 4; ++i) {
    const int row = r0 + ty*4 + i;
    float v[4];
    #pragma unroll
    for (int j = 0; j < 4; ++j) {
      v[j] = acc[i][j] + br[j];
      if (ACT) v[j] = fmaxf(v[j], 0.0f);
    }
    size_t oidx;
    if (HEADOUT) {
      const int b = row >> 10, t = row & 1023;
      oidx = (((size_t)b*M_ + m)*T_ + t)*V_ + c0 + tx*4;
    } else {
      oidx = ((size_t)m*RR + row)*NN + c0 + tx*4;
    }
    if (RES) {
      const float4 rv = *(const float4*)&resid[oidx];
      v[0]+=rv.x; v[1]+=rv.y; v[2]+=rv.z; v[3]+=rv.w;
    }
    float4 ov; ov.x=v[0]; ov.y=v[1]; ov.z=v[2]; ov.w=v[3];
    *(float4*)&C[oidx] = ov;
  }
}

// ---------------- flash attention fp32, causal; block = one (m,b,h) x 64-query tile ----------------
__global__ __launch_bounds__(256, 2)
void k_attn(const float* __restrict__ qkv, float* __restrict__ o)
{
  const int qb = blockIdx.x;   // query tile 0..15
  const int hh = blockIdx.y;   // head 0..7
  const int mb = blockIdx.z;   // m*B+b 0..7
  const float* base = qkv + (size_t)mb*T_*(3*D_) + hh*(3*DK_);

  __shared__ float Qs[64][64];   // k-major: Qs[d][r]
  __shared__ float Ks[64][64];   // k-major: Ks[d][c]
  __shared__ float Vs[64][64];   // row-major: Vs[s][c]
  __shared__ float Ps[64][64];   // k-major: Ps[s][r]

  const int tid = threadIdx.x;
  const int ty = tid >> 4, tx = tid & 15;
  const int lr  = tid >> 2;          // 0..63
  const int ld0 = (tid & 3) * 4;     // 0,4,8,12

  { // stage Q transposed
    const float* qp = base + (size_t)(qb*64 + lr)*(3*D_);
    #pragma unroll
    for (int q4 = 0; q4 < 4; ++q4) {
      const int db = ld0 + q4*16;
      const float4 v = *(const float4*)&qp[db];
      Qs[db+0][lr] = v.x; Qs[db+1][lr] = v.y; Qs[db+2][lr] = v.z; Qs[db+3][lr] = v.w;
    }
  }

  float m_i[4], l_i[4], O[4][4];
  #pragma unroll
  for (int i = 0; i < 4; ++i) {
    m_i[i] = -3.0e38f; l_i[i] = 0.0f;
    #pragma unroll
    for (int j = 0; j < 4; ++j) O[i][j] = 0.0f;
  }

  for (int kb = 0; kb <= qb; ++kb) {
    const float* kp = base + (size_t)(kb*64 + lr)*(3*D_) + DK_;
    const float* vp = kp + DK_;
    float4 kv[4], vv[4];
    #pragma unroll
    for (int q4 = 0; q4 < 4; ++q4) {
      kv[q4] = *(const float4*)&kp[ld0 + q4*16];
      vv[q4] = *(const float4*)&vp[ld0 + q4*16];
    }
    __syncthreads();   // previous iteration's consumers are done
    #pragma unroll
    for (int q4 = 0; q4 < 4; ++q4) {
      const int db = ld0 + q4*16;
      Ks[db+0][lr] = kv[q4].x; Ks[db+1][lr] = kv[q4].y;
      Ks[db+2][lr] = kv[q4].z; Ks[db+3][lr] = kv[q4].w;
      *(float4*)&Vs[lr][db] = vv[q4];
    }
    __syncthreads();

    // S = Q K^T (64x64), 4x4 per thread
    float s[4][4] = {};
    #pragma unroll 16
    for (int d = 0; d < 64; ++d) {
      const float4 qv = *(const float4*)&Qs[d][ty*4];
      const float4 kk = *(const float4*)&Ks[d][tx*4];
      const float qr[4] = {qv.x,qv.y,qv.z,qv.w};
      const float kr[4] = {kk.x,kk.y,kk.z,kk.w};
      #pragma unroll
      for (int i = 0; i < 4; ++i)
        #pragma unroll
        for (int j = 0; j < 4; ++j)
          s[i][j] = fmaf(qr[i], kr[j], s[i][j]);
    }

    // online softmax; a row's 16 owning lanes are contiguous within a wave
    float p[4][4];
    #pragma unroll
    for (int i = 0; i < 4; ++i) {
      #pragma unroll
      for (int j = 0; j < 4; ++j) {
        float sv = s[i][j] * 0.125f;                       // 1/sqrt(64)
        if (kb == qb && (tx*4+j) > (ty*4+i)) sv = -3.0e38f; // causal mask
        s[i][j] = sv;
      }
      float rm = fmaxf(fmaxf(s[i][0], s[i][1]), fmaxf(s[i][2], s[i][3]));
      rm = fmaxf(rm, __shfl_xor(rm, 1));
      rm = fmaxf(rm, __shfl_xor(rm, 2));
      rm = fmaxf(rm, __shfl_xor(rm, 4));
      rm = fmaxf(rm, __shfl_xor(rm, 8));
      const float mn = fmaxf(m_i[i], rm);
      const float sc = __expf(m_i[i] - mn);
      float rs = 0.0f;
      #pragma unroll
      for (int j = 0; j < 4; ++j) { p[i][j] = __expf(s[i][j] - mn); rs += p[i][j]; }
      rs += __shfl_xor(rs, 1);
      rs += __shfl_xor(rs, 2);
      rs += __shfl_xor(rs, 4);
      rs += __shfl_xor(rs, 8);
      l_i[i] = l_i[i]*sc + rs;
      m_i[i] = mn;
      #pragma unroll
      for (int j = 0; j < 4; ++j) O[i][j] *= sc;
    }

    // P -> LDS (k-major for PV)
    #pragma unroll
    for (int i = 0; i < 4; ++i)
      #pragma unroll
      for (int j = 0; j < 4; ++j)
        Ps[tx*4+j][ty*4+i] = p[i][j];
    __syncthreads();

    // O += P V
    #pragma unroll 16
    for (int ss = 0; ss < 64; ++ss) {
      const float4 pv4 = *(const float4*)&Ps[ss][ty*4];
      const float4 vv4 = *(const float4*)&Vs[ss][tx*4];
      const float pr[4] = {pv4.x,pv4.y,pv4.z,pv4.w};
      const float vr[4] = {vv4.x,vv4.y,vv4.z,vv4.w};
      #pragma unroll
      for (int i = 0; i < 4; ++i)
        #pragma unroll
        for (int j = 0; j < 4; ++j)
          O[i][j] = fmaf(pr[i], vr[j], O[i][j]);
    }
  }

  #pragma unroll
  for (int i = 0; i < 4; ++i) {
    const float inv = 1.0f / l_i[i];
    const int t = qb*64 + ty*4 + i;
    float4 ov;
    ov.x = O[i][0]*inv; ov.y = O[i][1]*inv; ov.z = O[i][2]*inv; ov.w = O[i][3]*inv;
    *(float4*)&o[((size_t)mb*T_ + t)*D_ + hh*DK_ + tx*4] = ov;
  }
}

extern "C" void kernel_launch(void* const* d_in, const int* in_sizes, int n_in,
                              void* d_out, int out_size, void* d_ws, size_t ws_size,
                              hipStream_t stream)
{
  const int*   x       = (const int*)  d_in[0];
  const float* tok_emb = (const float*)d_in[1];
  const float* pos_emb = (const float*)d_in[2];
  const float* ln1_w   = (const float*)d_in[3];
  const float* ln1_b   = (const float*)d_in[4];
  const float* qkv_w   = (const float*)d_in[5];
  const float* qkv_b   = (const float*)d_in[6];
  const float* out_w   = (const float*)d_in[7];
  const float* out_b   = (const float*)d_in[8];
  const float* ln2_w   = (const float*)d_in[9];
  const float* ln2_b   = (const float*)d_in[10];
  const float* ff1_w   = (const float*)d_in[11];
  const float* ff1_b   = (const float*)d_in[12];
  const float* ff2_w   = (const float*)d_in[13];
  const float* ff2_b   = (const float*)d_in[14];
  const float* lnf_w   = (const float*)d_in[15];
  const float* lnf_b   = (const float*)d_in[16];
  const float* head_w  = (const float*)d_in[17];
  const float* head_b  = (const float*)d_in[18];
  float* outp = (float*)d_out;

  float* ws = (float*)d_ws;
  const size_t HS = (size_t)M_*B_*T_*D_;            // 4,194,304 floats
  float* h   = ws;
  float* n   = h + HS;
  float* qkv = n + HS;                              // 12,582,912 floats
  float* o   = qkv + (size_t)M_*B_*T_*3*D_;         // 4,194,304 floats
  float* f   = qkv;                                 // FF act overlays dead qkv+o (16.8M floats)

  const int ROWS = M_*B_*T_;

  k_embed<<<dim3(T_, B_, M_), 128, 0, stream>>>(x, tok_emb, pos_emb, h);

  for (int l = 0; l < L_; ++l) {
    k_ln<<<ROWS, 256, 0, stream>>>(h, ln1_w + l*M_*D_, ln1_b + l*M_*D_, n);
    k_gemm<0,0,0><<<dim3(BT_/64, (3*D_)/64, M_), 256, 0, stream>>>(
        n, qkv_w + (size_t)l*M_*3*D_*D_, qkv_b + l*M_*3*D_, nullptr, qkv, BT_, 3*D_, D_);
    k_attn<<<dim3(T_/64, H_, M_*B_), 256, 0, stream>>>(qkv, o);
    k_gemm<0,1,0><<<dim3(BT_/64, D_/64, M_), 256, 0, stream>>>(
        o, out_w + (size_t)l*M_*D_*D_, out_b + l*M_*D_, h, h, BT_, D_, D_);
    k_ln<<<ROWS, 256, 0, stream>>>(h, ln2_w + l*M_*D_, ln2_b + l*M_*D_, n);
    k_gemm<1,0,0><<<dim3(BT_/64, FF_/64, M_), 256, 0, stream>>>(
        n, ff1_w + (size_t)l*M_*FF_*D_, ff1_b + l*M_*FF_, nullptr, f, BT_, FF_, D_);
    k_gemm<0,1,0><<<dim3(BT_/64, D_/64, M_), 256, 0, stream>>>(
        f, ff2_w + (size_t)l*M_*D_*FF_, ff2_b + l*M_*D_, h, h, BT_, D_, FF_);
  }

  k_ln<<<ROWS, 256, 0, stream>>>(h, lnf_w, lnf_b, n);
  k_gemm<0,0,1><<<dim3(BT_/64, V_/64, M_), 256, 0, stream>>>(
      n, head_w, head_b, nullptr, outp, BT_, V_, D_);
}

// Round 2
// 1771.301 us; speedup vs baseline: 2.3367x; 2.3367x over previous
//
#include <hip/hip_runtime.h>

#define M_  4
#define B_  2
#define T_  1024
#define D_  512
#define V_  128
#define L_  4
#define H_  8
#define FF_ 2048
#define DK_ 64
#define BT_ (B_*T_)
#define EPS_ 1e-5f

typedef __attribute__((ext_vector_type(8))) short  bf16x8;
typedef __attribute__((ext_vector_type(4))) float  f32x4;
typedef __attribute__((ext_vector_type(8))) ushort ushort8v;

__device__ __forceinline__ float b2f(ushort u) {
  union { unsigned int i; float f; } c; c.i = ((unsigned int)u) << 16; return c.f;
}
__device__ __forceinline__ ushort f2b(float f) {
  union { float f; unsigned int i; } c; c.f = f;
  return (ushort)((c.i + 0x7FFFu + ((c.i >> 16) & 1u)) >> 16);
}
__device__ __forceinline__ void gload_lds16(const void* g, void* l) {
  __builtin_amdgcn_global_load_lds((const __attribute__((address_space(1))) unsigned int*)g,
                                   (__attribute__((address_space(3))) unsigned int*)l, 16, 0, 0);
}

// ---------------- embedding: h[m,b,t,:] = tok[m, x[b,t], :] + pos[m, t, :] ----------------
__global__ __launch_bounds__(128)
void k_embed(const int* __restrict__ x, const float* __restrict__ tok,
             const float* __restrict__ pos, float* __restrict__ h)
{
  const int t = blockIdx.x, b = blockIdx.y, m = blockIdx.z;
  const int d = threadIdx.x * 4;
  const int xv = x[b*T_ + t];
  const float4 tv = *(const float4*)&tok[((size_t)m*V_ + xv)*D_ + d];
  const float4 pv = *(const float4*)&pos[((size_t)m*1024 + t)*D_ + d];
  float4 r;
  r.x = tv.x + pv.x; r.y = tv.y + pv.y; r.z = tv.z + pv.z; r.w = tv.w + pv.w;
  *(float4*)&h[(((size_t)m*B_ + b)*T_ + t)*D_ + d] = r;
}

// ---------------- fp32 -> bf16 bulk convert (8 elems/thread) ----------------
__global__ __launch_bounds__(256)
void k_cvt(const float* __restrict__ src, ushort* __restrict__ dst, int n8)
{
  const int i = blockIdx.x * 256 + threadIdx.x;
  if (i >= n8) return;
  const float4 a = ((const float4*)src)[i*2];
  const float4 b = ((const float4*)src)[i*2+1];
  ushort8v o;
  o[0]=f2b(a.x); o[1]=f2b(a.y); o[2]=f2b(a.z); o[3]=f2b(a.w);
  o[4]=f2b(b.x); o[5]=f2b(b.y); o[6]=f2b(b.z); o[7]=f2b(b.w);
  ((ushort8v*)dst)[i] = o;
}

// ---------------- layernorm over D=512; fp32 in, bf16 out ----------------
__global__ __launch_bounds__(256)
void k_ln(const float* __restrict__ x, const float* __restrict__ w,
          const float* __restrict__ bb, ushort* __restrict__ y)
{
  const int row = blockIdx.x;
  const int m = row / BT_;
  const int tid = threadIdx.x;
  const float2 v = *(const float2*)&x[(size_t)row*D_ + tid*2];
  float s  = v.x + v.y;
  float s2 = v.x*v.x + v.y*v.y;
  #pragma unroll
  for (int off = 1; off < 64; off <<= 1) {
    s  += __shfl_xor(s, off);
    s2 += __shfl_xor(s2, off);
  }
  __shared__ float ls[4], ls2[4];
  if ((tid & 63) == 0) { ls[tid>>6] = s; ls2[tid>>6] = s2; }
  __syncthreads();
  s  = ls[0]+ls[1]+ls[2]+ls[3];
  s2 = ls2[0]+ls2[1]+ls2[2]+ls2[3];
  const float mu   = s * (1.0f/D_);
  const float var  = s2 * (1.0f/D_) - mu*mu;
  const float rstd = rsqrtf(var + EPS_);
  const float2 wv = *(const float2*)&w[m*D_ + tid*2];
  const float2 bv = *(const float2*)&bb[m*D_ + tid*2];
  ushort2 o;
  o.x = f2b((v.x - mu)*rstd*wv.x + bv.x);
  o.y = f2b((v.y - mu)*rstd*wv.y + bv.y);
  *(ushort2*)&y[(size_t)row*D_ + tid*2] = o;
}

// ---------------- MFMA GEMM: C[m,r,c] = sum_k A[m,r,k]*W[m,c,k] + bias[m,c] ----------------
// m97 structure: 128x128 tile, BK=32, 4 waves (2x2), 4x4 16x16x32 frags/wave,
// global_load_lds width-16 into linear LDS, 2 barriers per K-step.
template<int OUTBF, int ACT, int RES, int HEADOUT>
__global__ __launch_bounds__(256)
void k_gemm(const ushort* __restrict__ A, const ushort* __restrict__ W,
            const float* __restrict__ bias, const float* __restrict__ resid,
            void* __restrict__ C, int RR, int NN, int KK)
{
  const int m  = blockIdx.z;
  const int r0 = blockIdx.x * 128;
  const int c0 = blockIdx.y * 128;
  const ushort* Am = A + (size_t)m*RR*KK;
  const ushort* Wm = W + (size_t)m*NN*KK;

  __shared__ ushort As[128*32];
  __shared__ ushort Bs[128*32];

  const int tid  = threadIdx.x;
  const int lane = tid & 63;
  const int wave = tid >> 6;
  const int wr = wave >> 1, wc = wave & 1;
  const int fr = lane & 15;            // row/col within 16x16 frag
  const int fk = (lane >> 4) * 8;      // K sub-offset (bf16 elems)

  f32x4 acc[4][4];
  #pragma unroll
  for (int i = 0; i < 4; ++i)
    #pragma unroll
    for (int j = 0; j < 4; ++j)
      acc[i][j] = (f32x4){0.f,0.f,0.f,0.f};

  // staging: linear idx (16B units) = wave*128 + i*64 + lane; row = idx>>2, kpart = (idx&3)*8
  const int sidx0 = wave*128 + lane;

  for (int k0 = 0; k0 < KK; k0 += 32) {
    #pragma unroll
    for (int i = 0; i < 2; ++i) {
      const int idx = sidx0 + i*64;
      const int row = idx >> 2, kp = (idx & 3) * 8;
      gload_lds16(Am + (size_t)(r0+row)*KK + k0 + kp, As + wave*1024 + i*512);
      gload_lds16(Wm + (size_t)(c0+row)*KK + k0 + kp, Bs + wave*1024 + i*512);
    }
    __syncthreads();   // vmcnt(0) drained by compiler before barrier

    bf16x8 af[4], bfv[4];
    #pragma unroll
    for (int i = 0; i < 4; ++i) {
      af[i]  = *(const bf16x8*)&As[(wr*64 + i*16 + fr)*32 + fk];
      bfv[i] = *(const bf16x8*)&Bs[(wc*64 + i*16 + fr)*32 + fk];
    }
    #pragma unroll
    for (int i = 0; i < 4; ++i)
      #pragma unroll
      for (int j = 0; j < 4; ++j)
        acc[i][j] = __builtin_amdgcn_mfma_f32_16x16x32_bf16(af[i], bfv[j], acc[i][j], 0, 0, 0);
    __syncthreads();   // protect LDS before next stage
  }

  // epilogue: C/D layout col=lane&15, row=(lane>>4)*4+reg
  const int colb = c0 + wc*64 + fr;
  float bi[4];
  #pragma unroll
  for (int j = 0; j < 4; ++j) bi[j] = bias[(size_t)m*NN + colb + j*16];

  #pragma unroll
  for (int i = 0; i < 4; ++i) {
    #pragma unroll
    for (int r = 0; r < 4; ++r) {
      const int row = r0 + wr*64 + i*16 + (lane>>4)*4 + r;
      #pragma unroll
      for (int j = 0; j < 4; ++j) {
        float val = acc[i][j][r] + bi[j];
        if (ACT) val = fmaxf(val, 0.0f);
        size_t oidx;
        if (HEADOUT) {
          const int b = row >> 10, t = row & 1023;
          oidx = (((size_t)b*M_ + m)*T_ + t)*V_ + colb + j*16;
        } else {
          oidx = ((size_t)m*RR + row)*NN + colb + j*16;
        }
        if (RES) val += resid[oidx];
        if (OUTBF) ((ushort*)C)[oidx] = f2b(val);
        else       ((float*)C)[oidx]  = val;
      }
    }
  }
}

// ---------------- flash attention fp32 compute, bf16 I/O; causal ----------------
__global__ __launch_bounds__(256, 2)
void k_attn(const ushort* __restrict__ qkv, ushort* __restrict__ o)
{
  const int qb = blockIdx.x;   // query tile 0..15
  const int hh = blockIdx.y;   // head 0..7
  const int mb = blockIdx.z;   // m*B+b 0..7
  const ushort* base = qkv + (size_t)mb*T_*(3*D_) + hh*(3*DK_);

  __shared__ float Qs[64][64];   // k-major: Qs[d][r]
  __shared__ float Ks[64][64];   // k-major: Ks[d][c]
  __shared__ float Vs[64][64];   // row-major: Vs[s][c]
  __shared__ float Ps[64][64];   // k-major: Ps[s][r]

  const int tid = threadIdx.x;
  const int ty = tid >> 4, tx = tid & 15;
  const int lr  = tid >> 2;          // 0..63
  const int ld0 = (tid & 3) * 4;     // 0,4,8,12

  { // stage Q transposed
    const ushort* qp = base + (size_t)(qb*64 + lr)*(3*D_);
    #pragma unroll
    for (int q4 = 0; q4 < 4; ++q4) {
      const int db = ld0 + q4*16;
      const ushort4 v = *(const ushort4*)&qp[db];
      Qs[db+0][lr] = b2f(v.x); Qs[db+1][lr] = b2f(v.y);
      Qs[db+2][lr] = b2f(v.z); Qs[db+3][lr] = b2f(v.w);
    }
  }

  float m_i[4], l_i[4], O[4][4];
  #pragma unroll
  for (int i = 0; i < 4; ++i) {
    m_i[i] = -3.0e38f; l_i[i] = 0.0f;
    #pragma unroll
    for (int j = 0; j < 4; ++j) O[i][j] = 0.0f;
  }

  for (int kb = 0; kb <= qb; ++kb) {
    const ushort* kp = base + (size_t)(kb*64 + lr)*(3*D_) + DK_;
    const ushort* vp = kp + DK_;
    ushort4 kv[4], vv[4];
    #pragma unroll
    for (int q4 = 0; q4 < 4; ++q4) {
      kv[q4] = *(const ushort4*)&kp[ld0 + q4*16];
      vv[q4] = *(const ushort4*)&vp[ld0 + q4*16];
    }
    __syncthreads();   // previous iteration's consumers are done
    #pragma unroll
    for (int q4 = 0; q4 < 4; ++q4) {
      const int db = ld0 + q4*16;
      Ks[db+0][lr] = b2f(kv[q4].x); Ks[db+1][lr] = b2f(kv[q4].y);
      Ks[db+2][lr] = b2f(kv[q4].z); Ks[db+3][lr] = b2f(kv[q4].w);
      float4 vf; vf.x = b2f(vv[q4].x); vf.y = b2f(vv[q4].y);
      vf.z = b2f(vv[q4].z); vf.w = b2f(vv[q4].w);
      *(float4*)&Vs[lr][db] = vf;
    }
    __syncthreads();

    // S = Q K^T (64x64), 4x4 per thread
    float s[4][4] = {};
    #pragma unroll 16
    for (int d = 0; d < 64; ++d) {
      const float4 qv = *(const float4*)&Qs[d][ty*4];
      const float4 kk = *(const float4*)&Ks[d][tx*4];
      const float qr[4] = {qv.x,qv.y,qv.z,qv.w};
      const float kr[4] = {kk.x,kk.y,kk.z,kk.w};
      #pragma unroll
      for (int i = 0; i < 4; ++i)
        #pragma unroll
        for (int j = 0; j < 4; ++j)
          s[i][j] = fmaf(qr[i], kr[j], s[i][j]);
    }

    // online softmax
    float p[4][4];
    #pragma unroll
    for (int i = 0; i < 4; ++i) {
      #pragma unroll
      for (int j = 0; j < 4; ++j) {
        float sv = s[i][j] * 0.125f;
        if (kb == qb && (tx*4+j) > (ty*4+i)) sv = -3.0e38f;
        s[i][j] = sv;
      }
      float rm = fmaxf(fmaxf(s[i][0], s[i][1]), fmaxf(s[i][2], s[i][3]));
      rm = fmaxf(rm, __shfl_xor(rm, 1));
      rm = fmaxf(rm, __shfl_xor(rm, 2));
      rm = fmaxf(rm, __shfl_xor(rm, 4));
      rm = fmaxf(rm, __shfl_xor(rm, 8));
      const float mn = fmaxf(m_i[i], rm);
      const float sc = __expf(m_i[i] - mn);
      float rs = 0.0f;
      #pragma unroll
      for (int j = 0; j < 4; ++j) { p[i][j] = __expf(s[i][j] - mn); rs += p[i][j]; }
      rs += __shfl_xor(rs, 1);
      rs += __shfl_xor(rs, 2);
      rs += __shfl_xor(rs, 4);
      rs += __shfl_xor(rs, 8);
      l_i[i] = l_i[i]*sc + rs;
      m_i[i] = mn;
      #pragma unroll
      for (int j = 0; j < 4; ++j) O[i][j] *= sc;
    }

    // P -> LDS (k-major for PV)
    #pragma unroll
    for (int i = 0; i < 4; ++i)
      #pragma unroll
      for (int j = 0; j < 4; ++j)
        Ps[tx*4+j][ty*4+i] = p[i][j];
    __syncthreads();

    // O += P V
    #pragma unroll 16
    for (int ss = 0; ss < 64; ++ss) {
      const float4 pv4 = *(const float4*)&Ps[ss][ty*4];
      const float4 vv4 = *(const float4*)&Vs[ss][tx*4];
      const float pr[4] = {pv4.x,pv4.y,pv4.z,pv4.w};
      const float vr[4] = {vv4.x,vv4.y,vv4.z,vv4.w};
      #pragma unroll
      for (int i = 0; i < 4; ++i)
        #pragma unroll
        for (int j = 0; j < 4; ++j)
          O[i][j] = fmaf(pr[i], vr[j], O[i][j]);
    }
  }

  #pragma unroll
  for (int i = 0; i < 4; ++i) {
    const float inv = 1.0f / l_i[i];
    const int t = qb*64 + ty*4 + i;
    ushort4 ov;
    ov.x = f2b(O[i][0]*inv); ov.y = f2b(O[i][1]*inv);
    ov.z = f2b(O[i][2]*inv); ov.w = f2b(O[i][3]*inv);
    *(ushort4*)&o[((size_t)mb*T_ + t)*D_ + hh*DK_ + tx*4] = ov;
  }
}

extern "C" void kernel_launch(void* const* d_in, const int* in_sizes, int n_in,
                              void* d_out, int out_size, void* d_ws, size_t ws_size,
                              hipStream_t stream)
{
  const int*   x       = (const int*)  d_in[0];
  const float* tok_emb = (const float*)d_in[1];
  const float* pos_emb = (const float*)d_in[2];
  const float* ln1_w   = (const float*)d_in[3];
  const float* ln1_b   = (const float*)d_in[4];
  const float* qkv_w   = (const float*)d_in[5];
  const float* qkv_b   = (const float*)d_in[6];
  const float* out_w   = (const float*)d_in[7];
  const float* out_b   = (const float*)d_in[8];
  const float* ln2_w   = (const float*)d_in[9];
  const float* ln2_b   = (const float*)d_in[10];
  const float* ff1_w   = (const float*)d_in[11];
  const float* ff1_b   = (const float*)d_in[12];
  const float* ff2_w   = (const float*)d_in[13];
  const float* ff2_b   = (const float*)d_in[14];
  const float* lnf_w   = (const float*)d_in[15];
  const float* lnf_b   = (const float*)d_in[16];
  const float* head_w  = (const float*)d_in[17];
  const float* head_b  = (const float*)d_in[18];
  float* outp = (float*)d_out;

  const size_t HS = (size_t)M_*B_*T_*D_;            // 4,194,304
  float*  h     = (float*)d_ws;                     // fp32 residual, 16.78 MB
  ushort* nb    = (ushort*)(h + HS);                // bf16 LN out, 8.39 MB
  ushort* unionA = nb + HS;                         // 33.55 MB region
  ushort* qkvb  = unionA;                           // 12.58M elems
  ushort* ob    = unionA + (size_t)M_*B_*T_*3*D_;   // 4.19M elems
  ushort* fb    = unionA;                           // overlay (16.78M elems)
  ushort* wbuf  = unionA + (size_t)M_*B_*T_*4*D_;   // 25.17 MB
  ushort* wq  = wbuf;                               // 3,145,728
  ushort* wo  = wbuf + 3145728;                     // 1,048,576
  ushort* wf1 = wbuf + 4194304;                     // 4,194,304
  ushort* wf2 = wbuf + 8388608;                     // 4,194,304

  const int ROWS = M_*B_*T_;
  const int NQ = M_*3*D_*D_ / 8, NO = M_*D_*D_ / 8, NF = M_*FF_*D_ / 8, NH = M_*V_*D_ / 8;

  k_embed<<<dim3(T_, B_, M_), 128, 0, stream>>>(x, tok_emb, pos_emb, h);

  for (int l = 0; l < L_; ++l) {
    k_cvt<<<NQ/256, 256, 0, stream>>>(qkv_w + (size_t)l*M_*3*D_*D_, wq, NQ);
    k_cvt<<<NO/256, 256, 0, stream>>>(out_w + (size_t)l*M_*D_*D_, wo, NO);
    k_cvt<<<NF/256, 256, 0, stream>>>(ff1_w + (size_t)l*M_*FF_*D_, wf1, NF);
    k_cvt<<<NF/256, 256, 0, stream>>>(ff2_w + (size_t)l*M_*D_*FF_, wf2, NF);

    k_ln<<<ROWS, 256, 0, stream>>>(h, ln1_w + l*M_*D_, ln1_b + l*M_*D_, nb);
    k_gemm<1,0,0,0><<<dim3(BT_/128, (3*D_)/128, M_), 256, 0, stream>>>(
        nb, wq, qkv_b + l*M_*3*D_, nullptr, qkvb, BT_, 3*D_, D_);
    k_attn<<<dim3(T_/64, H_, M_*B_), 256, 0, stream>>>(qkvb, ob);
    k_gemm<0,0,1,0><<<dim3(BT_/128, D_/128, M_), 256, 0, stream>>>(
        ob, wo, out_b + l*M_*D_, h, h, BT_, D_, D_);
    k_ln<<<ROWS, 256, 0, stream>>>(h, ln2_w + l*M_*D_, ln2_b + l*M_*D_, nb);
    k_gemm<1,1,0,0><<<dim3(BT_/128, FF_/128, M_), 256, 0, stream>>>(
        nb, wf1, ff1_b + l*M_*FF_, nullptr, fb, BT_, FF_, D_);
    k_gemm<0,0,1,0><<<dim3(BT_/128, D_/128, M_), 256, 0, stream>>>(
        fb, wf2, ff2_b + l*M_*D_, h, h, BT_, D_, FF_);
  }

  k_ln<<<ROWS, 256, 0, stream>>>(h, lnf_w, lnf_b, nb);
  k_cvt<<<NH/256, 256, 0, stream>>>(head_w, wq, NH);
  k_gemm<0,0,0,1><<<dim3(BT_/128, V_/128, M_), 256, 0, stream>>>(
      nb, wq, head_b, nullptr, outp, BT_, V_, D_);
}

// Round 3
// 955.775 us; speedup vs baseline: 4.3306x; 1.8533x over previous
//
#include <hip/hip_runtime.h>

#define M_  4
#define B_  2
#define T_  1024
#define D_  512
#define V_  128
#define L_  4
#define H_  8
#define FF_ 2048
#define DK_ 64
#define BT_ (B_*T_)
#define EPS_ 1e-5f

typedef __attribute__((ext_vector_type(8))) short  bf16x8;
typedef __attribute__((ext_vector_type(4))) float  f32x4;
typedef __attribute__((ext_vector_type(8))) ushort ushort8v;

__device__ __forceinline__ float b2f(ushort u) {
  union { unsigned int i; float f; } c; c.i = ((unsigned int)u) << 16; return c.f;
}
__device__ __forceinline__ ushort f2b(float f) {
  union { float f; unsigned int i; } c; c.f = f;
  return (ushort)((c.i + 0x7FFFu + ((c.i >> 16) & 1u)) >> 16);
}
__device__ __forceinline__ void gload_lds16(const void* g, void* l) {
  __builtin_amdgcn_global_load_lds((const __attribute__((address_space(1))) unsigned int*)g,
                                   (__attribute__((address_space(3))) unsigned int*)l, 16, 0, 0);
}

// ---------------- embedding ----------------
__global__ __launch_bounds__(128)
void k_embed(const int* __restrict__ x, const float* __restrict__ tok,
             const float* __restrict__ pos, float* __restrict__ h)
{
  const int t = blockIdx.x, b = blockIdx.y, m = blockIdx.z;
  const int d = threadIdx.x * 4;
  const int xv = x[b*T_ + t];
  const float4 tv = *(const float4*)&tok[((size_t)m*V_ + xv)*D_ + d];
  const float4 pv = *(const float4*)&pos[((size_t)m*1024 + t)*D_ + d];
  float4 r;
  r.x = tv.x + pv.x; r.y = tv.y + pv.y; r.z = tv.z + pv.z; r.w = tv.w + pv.w;
  *(float4*)&h[(((size_t)m*B_ + b)*T_ + t)*D_ + d] = r;
}

// ---------------- fp32 -> bf16 bulk convert ----------------
__global__ __launch_bounds__(256)
void k_cvt(const float* __restrict__ src, ushort* __restrict__ dst, int n8)
{
  const int i = blockIdx.x * 256 + threadIdx.x;
  if (i >= n8) return;
  const float4 a = ((const float4*)src)[i*2];
  const float4 b = ((const float4*)src)[i*2+1];
  ushort8v o;
  o[0]=f2b(a.x); o[1]=f2b(a.y); o[2]=f2b(a.z); o[3]=f2b(a.w);
  o[4]=f2b(b.x); o[5]=f2b(b.y); o[6]=f2b(b.z); o[7]=f2b(b.w);
  ((ushort8v*)dst)[i] = o;
}

// ---------------- layernorm (fp32 in, bf16 out) ----------------
__global__ __launch_bounds__(256)
void k_ln(const float* __restrict__ x, const float* __restrict__ w,
          const float* __restrict__ bb, ushort* __restrict__ y)
{
  const int row = blockIdx.x;
  const int m = row / BT_;
  const int tid = threadIdx.x;
  const float2 v = *(const float2*)&x[(size_t)row*D_ + tid*2];
  float s  = v.x + v.y;
  float s2 = v.x*v.x + v.y*v.y;
  #pragma unroll
  for (int off = 1; off < 64; off <<= 1) {
    s  += __shfl_xor(s, off);
    s2 += __shfl_xor(s2, off);
  }
  __shared__ float ls[4], ls2[4];
  if ((tid & 63) == 0) { ls[tid>>6] = s; ls2[tid>>6] = s2; }
  __syncthreads();
  s  = ls[0]+ls[1]+ls[2]+ls[3];
  s2 = ls2[0]+ls2[1]+ls2[2]+ls2[3];
  const float mu   = s * (1.0f/D_);
  const float var  = s2 * (1.0f/D_) - mu*mu;
  const float rstd = rsqrtf(var + EPS_);
  const float2 wv = *(const float2*)&w[m*D_ + tid*2];
  const float2 bv = *(const float2*)&bb[m*D_ + tid*2];
  ushort2 o;
  o.x = f2b((v.x - mu)*rstd*wv.x + bv.x);
  o.y = f2b((v.y - mu)*rstd*wv.y + bv.y);
  *(ushort2*)&y[(size_t)row*D_ + tid*2] = o;
}

// ---------------- MFMA GEMM (m97 structure) ----------------
// SPLITV: qkv GEMM — Q,K cols -> C token-major; V cols -> vt[(mbg*8+h)*64+d][t]
template<int OUTBF, int ACT, int RES, int HEADOUT, int SPLITV>
__global__ __launch_bounds__(256)
void k_gemm(const ushort* __restrict__ A, const ushort* __restrict__ W,
            const float* __restrict__ bias, const float* __restrict__ resid,
            void* __restrict__ C, ushort* __restrict__ vt, int RR, int NN, int KK)
{
  const int m  = blockIdx.z;
  const int r0 = blockIdx.x * 128;
  const int c0 = blockIdx.y * 128;
  const ushort* Am = A + (size_t)m*RR*KK;
  const ushort* Wm = W + (size_t)m*NN*KK;

  __shared__ ushort As[128*32];
  __shared__ ushort Bs[128*32];

  const int tid  = threadIdx.x;
  const int lane = tid & 63;
  const int wave = tid >> 6;
  const int wr = wave >> 1, wc = wave & 1;
  const int fr = lane & 15;
  const int fk = (lane >> 4) * 8;

  f32x4 acc[4][4];
  #pragma unroll
  for (int i = 0; i < 4; ++i)
    #pragma unroll
    for (int j = 0; j < 4; ++j)
      acc[i][j] = (f32x4){0.f,0.f,0.f,0.f};

  const int sidx0 = wave*128 + lane;

  for (int k0 = 0; k0 < KK; k0 += 32) {
    #pragma unroll
    for (int i = 0; i < 2; ++i) {
      const int idx = sidx0 + i*64;
      const int row = idx >> 2, kp = (idx & 3) * 8;
      gload_lds16(Am + (size_t)(r0+row)*KK + k0 + kp, As + wave*1024 + i*512);
      gload_lds16(Wm + (size_t)(c0+row)*KK + k0 + kp, Bs + wave*1024 + i*512);
    }
    __syncthreads();

    bf16x8 af[4], bfv[4];
    #pragma unroll
    for (int i = 0; i < 4; ++i) {
      af[i]  = *(const bf16x8*)&As[(wr*64 + i*16 + fr)*32 + fk];
      bfv[i] = *(const bf16x8*)&Bs[(wc*64 + i*16 + fr)*32 + fk];
    }
    #pragma unroll
    for (int i = 0; i < 4; ++i)
      #pragma unroll
      for (int j = 0; j < 4; ++j)
        acc[i][j] = __builtin_amdgcn_mfma_f32_16x16x32_bf16(af[i], bfv[j], acc[i][j], 0, 0, 0);
    __syncthreads();
  }

  const int colb = c0 + wc*64 + fr;
  float bi[4];
  #pragma unroll
  for (int j = 0; j < 4; ++j) bi[j] = bias[(size_t)m*NN + colb + j*16];

  #pragma unroll
  for (int i = 0; i < 4; ++i) {
    #pragma unroll
    for (int r = 0; r < 4; ++r) {
      const int row = r0 + wr*64 + i*16 + (lane>>4)*4 + r;
      #pragma unroll
      for (int j = 0; j < 4; ++j) {
        float val = acc[i][j][r] + bi[j];
        if (ACT) val = fmaxf(val, 0.0f);
        const int col = colb + j*16;
        if (SPLITV) {
          const int hh2 = col / 192;
          const int sub = col - hh2*192;
          if (sub >= 128) {
            const int mbg = m*B_ + (row >> 10);
            const int t = row & 1023;
            vt[(((size_t)mbg*8 + hh2)*64 + (sub-128))*1024 + t] = f2b(val);
          } else {
            ((ushort*)C)[((size_t)m*RR + row)*NN + col] = f2b(val);
          }
        } else {
          size_t oidx;
          if (HEADOUT) {
            const int b = row >> 10, t = row & 1023;
            oidx = (((size_t)b*M_ + m)*T_ + t)*V_ + col;
          } else {
            oidx = ((size_t)m*RR + row)*NN + col;
          }
          float v2 = val;
          if (RES) v2 += resid[oidx];
          if (OUTBF) ((ushort*)C)[oidx] = f2b(v2);
          else       ((float*)C)[oidx]  = v2;
        }
      }
    }
  }
}

// ---------------- MFMA flash attention ----------------
// block: (qb, h, mbg); 4 waves x 16 q-rows. Q,K token-major from qkvb; V from vt [d][T].
__global__ __launch_bounds__(256)
void k_attn_mfma(const ushort* __restrict__ qkvb, const ushort* __restrict__ vt,
                 ushort* __restrict__ o)
{
  const int qb  = blockIdx.x;
  const int hh  = blockIdx.y;
  const int mbg = blockIdx.z;

  __shared__ ushort Qs[64*64];
  __shared__ ushort Ks[64*64];
  __shared__ ushort Vs[64*64];     // V^T tile: row=d, col=k_local
  __shared__ ushort Ps[4][16*80];  // per-wave P, stride 80 (bank-rotating)

  const int tid  = threadIdx.x;
  const int lane = tid & 63;
  const int wave = tid >> 6;
  const int fr = lane & 15;
  const int fq = lane >> 4;

  const ushort* qk_base = qkvb + (size_t)mbg*T_*(3*D_) + hh*(3*DK_);
  const ushort* vt_base = vt + ((size_t)(mbg*8 + hh)*64)*1024;

  // stage Q (pre-swizzled global source -> linear LDS; read side XORs (row&7))
  #pragma unroll
  for (int i = 0; i < 2; ++i) {
    const int c = wave*128 + i*64 + lane;
    const int row = c >> 3, ch = c & 7;
    gload_lds16(qk_base + (size_t)(qb*64 + row)*(3*D_) + ((ch ^ (row&7))*8),
                (ushort*)Qs + (size_t)(wave*128 + i*64)*8);
  }
  // stage K,V tile 0
  #pragma unroll
  for (int i = 0; i < 2; ++i) {
    const int c = wave*128 + i*64 + lane;
    const int row = c >> 3, ch = c & 7;
    gload_lds16(qk_base + (size_t)row*(3*D_) + DK_ + ((ch ^ (row&7))*8),
                (ushort*)Ks + (size_t)(wave*128 + i*64)*8);
    gload_lds16(vt_base + (size_t)row*1024 + ((ch ^ (row&7))*8),
                (ushort*)Vs + (size_t)(wave*128 + i*64)*8);
  }
  __syncthreads();

  // hoist Q fragments (Qs is never overwritten)
  bf16x8 aQ[2];
  #pragma unroll
  for (int kc = 0; kc < 2; ++kc) {
    const int qrow = wave*16 + fr;
    aQ[kc] = *(const bf16x8*)&Qs[qrow*64 + (((kc*4 + fq) ^ (qrow&7))*8)];
  }

  float m_i[4], l_i[4];
  f32x4 Of[4];
  #pragma unroll
  for (int r = 0; r < 4; ++r) { m_i[r] = -3.0e38f; l_i[r] = 0.0f; }
  #pragma unroll
  for (int j = 0; j < 4; ++j) Of[j] = (f32x4){0.f,0.f,0.f,0.f};

  const int qrow_abs0 = qb*64 + wave*16 + fq*4;

  for (int kb = 0; kb <= qb; ++kb) {
    if (kb > 0) {
      #pragma unroll
      for (int i = 0; i < 2; ++i) {
        const int c = wave*128 + i*64 + lane;
        const int row = c >> 3, ch = c & 7;
        gload_lds16(qk_base + (size_t)(kb*64 + row)*(3*D_) + DK_ + ((ch ^ (row&7))*8),
                    (ushort*)Ks + (size_t)(wave*128 + i*64)*8);
        gload_lds16(vt_base + (size_t)row*1024 + kb*64 + ((ch ^ (row&7))*8),
                    (ushort*)Vs + (size_t)(wave*128 + i*64)*8);
      }
      __syncthreads();
    }

    // S = Q K^T : 16x64 per wave
    f32x4 acc[4];
    #pragma unroll
    for (int j = 0; j < 4; ++j) acc[j] = (f32x4){0.f,0.f,0.f,0.f};
    #pragma unroll
    for (int kc = 0; kc < 2; ++kc) {
      #pragma unroll
      for (int j = 0; j < 4; ++j) {
        const int krow = j*16 + fr;
        const bf16x8 bK = *(const bf16x8*)&Ks[krow*64 + (((kc*4 + fq) ^ (krow&7))*8)];
        acc[j] = __builtin_amdgcn_mfma_f32_16x16x32_bf16(aQ[kc], bK, acc[j], 0, 0, 0);
      }
    }

    // online softmax (rows r: q = qrow_abs0 + r; cols: kb*64 + j*16 + fr)
    float p[4][4];
    #pragma unroll
    for (int r = 0; r < 4; ++r) {
      float sv[4];
      #pragma unroll
      for (int j = 0; j < 4; ++j) {
        sv[j] = acc[j][r] * 0.125f;
        if (kb == qb && (kb*64 + j*16 + fr) > (qrow_abs0 + r)) sv[j] = -3.0e38f;
      }
      float rm = fmaxf(fmaxf(sv[0], sv[1]), fmaxf(sv[2], sv[3]));
      rm = fmaxf(rm, __shfl_xor(rm, 1));
      rm = fmaxf(rm, __shfl_xor(rm, 2));
      rm = fmaxf(rm, __shfl_xor(rm, 4));
      rm = fmaxf(rm, __shfl_xor(rm, 8));
      const float mn = fmaxf(m_i[r], rm);
      const float sc = __expf(m_i[r] - mn);
      m_i[r] = mn;
      float rs = 0.0f;
      #pragma unroll
      for (int j = 0; j < 4; ++j) { p[r][j] = __expf(sv[j] - mn); rs += p[r][j]; }
      rs += __shfl_xor(rs, 1);
      rs += __shfl_xor(rs, 2);
      rs += __shfl_xor(rs, 4);
      rs += __shfl_xor(rs, 8);
      l_i[r] = l_i[r]*sc + rs;
      #pragma unroll
      for (int j = 0; j < 4; ++j) Of[j][r] *= sc;
    }

    // P -> per-wave LDS (accum layout -> A-frag layout); XOR (row>>2)<<4 on both sides
    #pragma unroll
    for (int r = 0; r < 4; ++r)
      #pragma unroll
      for (int j = 0; j < 4; ++j) {
        const int prow = fq*4 + r;
        const int idx = prow*80 + j*16 + fr;
        Ps[wave][idx ^ ((prow>>2)<<4)] = f2b(p[r][j]);
      }

    // O += P V
    #pragma unroll
    for (int kc = 0; kc < 2; ++kc) {
      const int pidx = fr*80 + kc*32 + fq*8;
      const bf16x8 pa = *(const bf16x8*)&Ps[wave][pidx ^ ((fr>>2)<<4)];
      #pragma unroll
      for (int j = 0; j < 4; ++j) {
        const int vrow = j*16 + fr;
        const bf16x8 bV = *(const bf16x8*)&Vs[vrow*64 + (((kc*4 + fq) ^ (vrow&7))*8)];
        Of[j] = __builtin_amdgcn_mfma_f32_16x16x32_bf16(pa, bV, Of[j], 0, 0, 0);
      }
    }
    __syncthreads();
  }

  // epilogue: O[q][d] -> o[mbg][t][hh*64+d]
  #pragma unroll
  for (int r = 0; r < 4; ++r) {
    const float inv = 1.0f / l_i[r];
    const int t = qrow_abs0 - qb*64 + qb*64 + r;  // = qrow_abs0 + r
    ushort* op = o + ((size_t)mbg*T_ + (qrow_abs0 + r))*D_ + hh*DK_ + fr;
    #pragma unroll
    for (int j = 0; j < 4; ++j)
      op[j*16] = f2b(Of[j][r] * inv);
  }
}

extern "C" void kernel_launch(void* const* d_in, const int* in_sizes, int n_in,
                              void* d_out, int out_size, void* d_ws, size_t ws_size,
                              hipStream_t stream)
{
  const int*   x       = (const int*)  d_in[0];
  const float* tok_emb = (const float*)d_in[1];
  const float* pos_emb = (const float*)d_in[2];
  const float* ln1_w   = (const float*)d_in[3];
  const float* ln1_b   = (const float*)d_in[4];
  const float* qkv_w   = (const float*)d_in[5];
  const float* qkv_b   = (const float*)d_in[6];
  const float* out_w   = (const float*)d_in[7];
  const float* out_b   = (const float*)d_in[8];
  const float* ln2_w   = (const float*)d_in[9];
  const float* ln2_b   = (const float*)d_in[10];
  const float* ff1_w   = (const float*)d_in[11];
  const float* ff1_b   = (const float*)d_in[12];
  const float* ff2_w   = (const float*)d_in[13];
  const float* ff2_b   = (const float*)d_in[14];
  const float* lnf_w   = (const float*)d_in[15];
  const float* lnf_b   = (const float*)d_in[16];
  const float* head_w  = (const float*)d_in[17];
  const float* head_b  = (const float*)d_in[18];
  float* outp = (float*)d_out;

  const size_t HS = (size_t)M_*B_*T_*D_;            // 4,194,304
  float*  h     = (float*)d_ws;                     // 16.78 MB
  ushort* nb    = (ushort*)(h + HS);                // 8.39 MB
  ushort* qkvb  = nb + HS;                          // 12.58M ushorts
  ushort* ob    = qkvb + (size_t)M_*B_*T_*3*D_;     // 4.19M ushorts
  ushort* fb    = qkvb;                             // overlay (16.78M ushorts)
  ushort* vtb   = ob + HS;                          // 4.19M ushorts (8.39 MB)
  ushort* wslot = vtb + HS;                         // 4.19M ushorts (8.39 MB)

  const int ROWS = M_*B_*T_;
  const int NQ = M_*3*D_*D_/8, NO = M_*D_*D_/8, NF = M_*FF_*D_/8, NH = M_*V_*D_/8;

  k_embed<<<dim3(T_, B_, M_), 128, 0, stream>>>(x, tok_emb, pos_emb, h);

  for (int l = 0; l < L_; ++l) {
    k_ln<<<ROWS, 256, 0, stream>>>(h, ln1_w + l*M_*D_, ln1_b + l*M_*D_, nb);

    k_cvt<<<NQ/256, 256, 0, stream>>>(qkv_w + (size_t)l*M_*3*D_*D_, wslot, NQ);
    k_gemm<1,0,0,0,1><<<dim3(BT_/128, (3*D_)/128, M_), 256, 0, stream>>>(
        nb, wslot, qkv_b + l*M_*3*D_, nullptr, qkvb, vtb, BT_, 3*D_, D_);

    k_attn_mfma<<<dim3(T_/64, H_, M_*B_), 256, 0, stream>>>(qkvb, vtb, ob);

    k_cvt<<<NO/256, 256, 0, stream>>>(out_w + (size_t)l*M_*D_*D_, wslot, NO);
    k_gemm<0,0,1,0,0><<<dim3(BT_/128, D_/128, M_), 256, 0, stream>>>(
        ob, wslot, out_b + l*M_*D_, h, h, nullptr, BT_, D_, D_);

    k_ln<<<ROWS, 256, 0, stream>>>(h, ln2_w + l*M_*D_, ln2_b + l*M_*D_, nb);

    k_cvt<<<NF/256, 256, 0, stream>>>(ff1_w + (size_t)l*M_*FF_*D_, wslot, NF);
    k_gemm<1,1,0,0,0><<<dim3(BT_/128, FF_/128, M_), 256, 0, stream>>>(
        nb, wslot, ff1_b + l*M_*FF_, nullptr, fb, nullptr, BT_, FF_, D_);

    k_cvt<<<NF/256, 256, 0, stream>>>(ff2_w + (size_t)l*M_*D_*FF_, wslot, NF);
    k_gemm<0,0,1,0,0><<<dim3(BT_/128, D_/128, M_), 256, 0, stream>>>(
        fb, wslot, ff2_b + l*M_*D_, h, h, nullptr, BT_, D_, FF_);
  }

  k_ln<<<ROWS, 256, 0, stream>>>(h, lnf_w, lnf_b, nb);
  k_cvt<<<NH/256, 256, 0, stream>>>(head_w, wslot, NH);
  k_gemm<0,0,0,1,0><<<dim3(BT_/128, V_/128, M_), 256, 0, stream>>>(
      nb, wslot, head_b, nullptr, outp, nullptr, BT_, V_, D_);
}

// Round 4
// 902.413 us; speedup vs baseline: 4.5867x; 1.0591x over previous
//
#include <hip/hip_runtime.h>

#define M_  4
#define B_  2
#define T_  1024
#define D_  512
#define V_  128
#define L_  4
#define H_  8
#define FF_ 2048
#define DK_ 64
#define BT_ (B_*T_)
#define EPS_ 1e-5f

typedef __attribute__((ext_vector_type(8))) short  bf16x8;
typedef __attribute__((ext_vector_type(4))) float  f32x4;
typedef __attribute__((ext_vector_type(8))) ushort ushort8v;

__device__ __forceinline__ float b2f(ushort u) {
  union { unsigned int i; float f; } c; c.i = ((unsigned int)u) << 16; return c.f;
}
__device__ __forceinline__ ushort f2b(float f) {
  union { float f; unsigned int i; } c; c.f = f;
  return (ushort)((c.i + 0x7FFFu + ((c.i >> 16) & 1u)) >> 16);
}
__device__ __forceinline__ void gload_lds16(const void* g, void* l) {
  __builtin_amdgcn_global_load_lds((const __attribute__((address_space(1))) unsigned int*)g,
                                   (__attribute__((address_space(3))) unsigned int*)l, 16, 0, 0);
}

// ---------------- embedding ----------------
__global__ __launch_bounds__(128)
void k_embed(const int* __restrict__ x, const float* __restrict__ tok,
             const float* __restrict__ pos, float* __restrict__ h)
{
  const int t = blockIdx.x, b = blockIdx.y, m = blockIdx.z;
  const int d = threadIdx.x * 4;
  const int xv = x[b*T_ + t];
  const float4 tv = *(const float4*)&tok[((size_t)m*V_ + xv)*D_ + d];
  const float4 pv = *(const float4*)&pos[((size_t)m*1024 + t)*D_ + d];
  float4 r;
  r.x = tv.x + pv.x; r.y = tv.y + pv.y; r.z = tv.z + pv.z; r.w = tv.w + pv.w;
  *(float4*)&h[(((size_t)m*B_ + b)*T_ + t)*D_ + d] = r;
}

// ---------------- fp32 -> bf16 bulk convert ----------------
__global__ __launch_bounds__(256)
void k_cvt(const float* __restrict__ src, ushort* __restrict__ dst, int n8)
{
  const int i = blockIdx.x * 256 + threadIdx.x;
  if (i >= n8) return;
  const float4 a = ((const float4*)src)[i*2];
  const float4 b = ((const float4*)src)[i*2+1];
  ushort8v o;
  o[0]=f2b(a.x); o[1]=f2b(a.y); o[2]=f2b(a.z); o[3]=f2b(a.w);
  o[4]=f2b(b.x); o[5]=f2b(b.y); o[6]=f2b(b.z); o[7]=f2b(b.w);
  ((ushort8v*)dst)[i] = o;
}

// ---------------- layernorm (fp32 in, bf16 out) ----------------
__global__ __launch_bounds__(256)
void k_ln(const float* __restrict__ x, const float* __restrict__ w,
          const float* __restrict__ bb, ushort* __restrict__ y)
{
  const int row = blockIdx.x;
  const int m = row / BT_;
  const int tid = threadIdx.x;
  const float2 v = *(const float2*)&x[(size_t)row*D_ + tid*2];
  float s  = v.x + v.y;
  float s2 = v.x*v.x + v.y*v.y;
  #pragma unroll
  for (int off = 1; off < 64; off <<= 1) {
    s  += __shfl_xor(s, off);
    s2 += __shfl_xor(s2, off);
  }
  __shared__ float ls[4], ls2[4];
  if ((tid & 63) == 0) { ls[tid>>6] = s; ls2[tid>>6] = s2; }
  __syncthreads();
  s  = ls[0]+ls[1]+ls[2]+ls[3];
  s2 = ls2[0]+ls2[1]+ls2[2]+ls2[3];
  const float mu   = s * (1.0f/D_);
  const float var  = s2 * (1.0f/D_) - mu*mu;
  const float rstd = rsqrtf(var + EPS_);
  const float2 wv = *(const float2*)&w[m*D_ + tid*2];
  const float2 bv = *(const float2*)&bb[m*D_ + tid*2];
  ushort2 o;
  o.x = f2b((v.x - mu)*rstd*wv.x + bv.x);
  o.y = f2b((v.y - mu)*rstd*wv.y + bv.y);
  *(ushort2*)&y[(size_t)row*D_ + tid*2] = o;
}

// ---------------- MFMA GEMM: 128x128 tile, BK=64, swizzled LDS ----------------
// SPLITV: qkv GEMM — Q,K cols -> C token-major; V cols -> vt[(mbg*8+h)*64+d][t]
template<int OUTBF, int ACT, int RES, int HEADOUT, int SPLITV>
__global__ __launch_bounds__(256)
void k_gemm(const ushort* __restrict__ A, const ushort* __restrict__ W,
            const float* __restrict__ bias, const float* __restrict__ resid,
            void* __restrict__ C, ushort* __restrict__ vt, int RR, int NN, int KK)
{
  const int m  = blockIdx.z;
  const int r0 = blockIdx.x * 128;
  const int c0 = blockIdx.y * 128;
  const ushort* Am = A + (size_t)m*RR*KK;
  const ushort* Wm = W + (size_t)m*NN*KK;

  __shared__ ushort As[128*64];
  __shared__ ushort Bs[128*64];

  const int tid  = threadIdx.x;
  const int lane = tid & 63;
  const int wave = tid >> 6;
  const int wr = wave >> 1, wc = wave & 1;
  const int fr = lane & 15;
  const int fq = lane >> 4;

  f32x4 acc[4][4];
  #pragma unroll
  for (int i = 0; i < 4; ++i)
    #pragma unroll
    for (int j = 0; j < 4; ++j)
      acc[i][j] = (f32x4){0.f,0.f,0.f,0.f};

  for (int k0 = 0; k0 < KK; k0 += 64) {
    #pragma unroll
    for (int i = 0; i < 4; ++i) {
      const int c = i*256 + tid;           // 16B chunk index, 0..1023
      const int row = c >> 3, ch = c & 7;
      const int sch = ch ^ (row & 7);      // pre-swizzled global source (rule 21)
      gload_lds16(Am + (size_t)(r0+row)*KK + k0 + sch*8, (ushort*)As + (size_t)c*8);
      gload_lds16(Wm + (size_t)(c0+row)*KK + k0 + sch*8, (ushort*)Bs + (size_t)c*8);
    }
    __syncthreads();

    #pragma unroll
    for (int kk = 0; kk < 2; ++kk) {
      bf16x8 af[4], bfv[4];
      #pragma unroll
      for (int i = 0; i < 4; ++i) {
        const int rowA = wr*64 + i*16 + fr;
        af[i]  = *(const bf16x8*)&As[rowA*64 + (((kk*4 + fq) ^ (rowA & 7))*8)];
        const int rowB = wc*64 + i*16 + fr;
        bfv[i] = *(const bf16x8*)&Bs[rowB*64 + (((kk*4 + fq) ^ (rowB & 7))*8)];
      }
      #pragma unroll
      for (int i = 0; i < 4; ++i)
        #pragma unroll
        for (int j = 0; j < 4; ++j)
          acc[i][j] = __builtin_amdgcn_mfma_f32_16x16x32_bf16(af[i], bfv[j], acc[i][j], 0, 0, 0);
    }
    __syncthreads();
  }

  const int colb = c0 + wc*64 + fr;
  float bi[4];
  #pragma unroll
  for (int j = 0; j < 4; ++j) bi[j] = bias[(size_t)m*NN + colb + j*16];

  #pragma unroll
  for (int i = 0; i < 4; ++i) {
    #pragma unroll
    for (int r = 0; r < 4; ++r) {
      const int row = r0 + wr*64 + i*16 + fq*4 + r;
      #pragma unroll
      for (int j = 0; j < 4; ++j) {
        float val = acc[i][j][r] + bi[j];
        if (ACT) val = fmaxf(val, 0.0f);
        const int col = colb + j*16;
        if (SPLITV) {
          const int hh2 = col / 192;
          const int sub = col - hh2*192;
          if (sub >= 128) {
            const int mbg = m*B_ + (row >> 10);
            const int t = row & 1023;
            vt[(((size_t)mbg*8 + hh2)*64 + (sub-128))*1024 + t] = f2b(val);
          } else {
            ((ushort*)C)[((size_t)m*RR + row)*NN + col] = f2b(val);
          }
        } else {
          size_t oidx;
          if (HEADOUT) {
            const int b = row >> 10, t = row & 1023;
            oidx = (((size_t)b*M_ + m)*T_ + t)*V_ + col;
          } else {
            oidx = ((size_t)m*RR + row)*NN + col;
          }
          float v2 = val;
          if (RES) v2 += resid[oidx];
          if (OUTBF) ((ushort*)C)[oidx] = f2b(v2);
          else       ((float*)C)[oidx]  = v2;
        }
      }
    }
  }
}

// ---------------- MFMA flash attention, 2-phase pipelined ----------------
__global__ __launch_bounds__(256)
void k_attn_mfma(const ushort* __restrict__ qkvb, const ushort* __restrict__ vt,
                 ushort* __restrict__ o)
{
  const int qb  = blockIdx.x;
  const int hh  = blockIdx.y;
  const int mbg = blockIdx.z;

  __shared__ ushort Qs[64*64];
  __shared__ ushort Ks[2][64*64];
  __shared__ ushort Vs[2][64*64];
  __shared__ ushort Ps[4][16*80];

  const int tid  = threadIdx.x;
  const int lane = tid & 63;
  const int wave = tid >> 6;
  const int fr = lane & 15;
  const int fq = lane >> 4;

  const ushort* qk_base = qkvb + (size_t)mbg*T_*(3*D_) + hh*(3*DK_);
  const ushort* vt_base = vt + ((size_t)(mbg*8 + hh)*64)*1024;

  // stage Q + K/V tile 0 (pre-swizzled global source -> linear LDS)
  #pragma unroll
  for (int i = 0; i < 2; ++i) {
    const int c = wave*128 + i*64 + lane;
    const int row = c >> 3, ch = c & 7;
    const int sch = (ch ^ (row & 7)) * 8;
    gload_lds16(qk_base + (size_t)(qb*64 + row)*(3*D_) + sch,
                (ushort*)Qs + (size_t)(wave*128 + i*64)*8);
    gload_lds16(qk_base + (size_t)row*(3*D_) + DK_ + sch,
                (ushort*)Ks[0] + (size_t)(wave*128 + i*64)*8);
    gload_lds16(vt_base + (size_t)row*1024 + sch,
                (ushort*)Vs[0] + (size_t)(wave*128 + i*64)*8);
  }
  __syncthreads();

  // hoist Q fragments
  bf16x8 aQ[2];
  #pragma unroll
  for (int kc = 0; kc < 2; ++kc) {
    const int qrow = wave*16 + fr;
    aQ[kc] = *(const bf16x8*)&Qs[qrow*64 + (((kc*4 + fq) ^ (qrow & 7))*8)];
  }

  float m_i[4], l_i[4];
  f32x4 Of[4];
  #pragma unroll
  for (int r = 0; r < 4; ++r) { m_i[r] = -3.0e38f; l_i[r] = 0.0f; }
  #pragma unroll
  for (int j = 0; j < 4; ++j) Of[j] = (f32x4){0.f,0.f,0.f,0.f};

  const int qrow_abs0 = qb*64 + wave*16 + fq*4;

  for (int kb = 0; kb <= qb; ++kb) {
    const int cur = kb & 1;

    // prefetch next K/V tile into the other buffer (completion guaranteed by
    // the barrier at the END of this iteration; safe to overwrite: last read
    // of buf cur^1 finished before the previous barrier)
    if (kb < qb) {
      #pragma unroll
      for (int i = 0; i < 2; ++i) {
        const int c = wave*128 + i*64 + lane;
        const int row = c >> 3, ch = c & 7;
        const int sch = (ch ^ (row & 7)) * 8;
        gload_lds16(qk_base + (size_t)((kb+1)*64 + row)*(3*D_) + DK_ + sch,
                    (ushort*)Ks[cur^1] + (size_t)(wave*128 + i*64)*8);
        gload_lds16(vt_base + (size_t)row*1024 + (kb+1)*64 + sch,
                    (ushort*)Vs[cur^1] + (size_t)(wave*128 + i*64)*8);
      }
    }

    // S = Q K^T : 16x64 per wave
    f32x4 acc[4];
    #pragma unroll
    for (int j = 0; j < 4; ++j) acc[j] = (f32x4){0.f,0.f,0.f,0.f};
    __builtin_amdgcn_s_setprio(1);
    #pragma unroll
    for (int kc = 0; kc < 2; ++kc) {
      #pragma unroll
      for (int j = 0; j < 4; ++j) {
        const int krow = j*16 + fr;
        const bf16x8 bK = *(const bf16x8*)&Ks[cur][krow*64 + (((kc*4 + fq) ^ (krow & 7))*8)];
        acc[j] = __builtin_amdgcn_mfma_f32_16x16x32_bf16(aQ[kc], bK, acc[j], 0, 0, 0);
      }
    }
    __builtin_amdgcn_s_setprio(0);

    // online softmax with defer-max (T13, THR=8)
    float sv[4][4], rm4[4];
    float ex = -3.0e38f;
    #pragma unroll
    for (int r = 0; r < 4; ++r) {
      #pragma unroll
      for (int j = 0; j < 4; ++j) {
        sv[r][j] = acc[j][r] * 0.125f;
        if (kb == qb && (kb*64 + j*16 + fr) > (qrow_abs0 + r)) sv[r][j] = -3.0e38f;
      }
      float rm = fmaxf(fmaxf(sv[r][0], sv[r][1]), fmaxf(sv[r][2], sv[r][3]));
      rm = fmaxf(rm, __shfl_xor(rm, 1));
      rm = fmaxf(rm, __shfl_xor(rm, 2));
      rm = fmaxf(rm, __shfl_xor(rm, 4));
      rm = fmaxf(rm, __shfl_xor(rm, 8));
      rm4[r] = rm;
      ex = fmaxf(ex, rm - m_i[r]);
    }
    if (!__all(ex <= 8.0f)) {
      #pragma unroll
      for (int r = 0; r < 4; ++r) {
        const float mn = fmaxf(m_i[r], rm4[r]);
        const float sc = __expf(m_i[r] - mn);
        m_i[r] = mn;
        l_i[r] *= sc;
        #pragma unroll
        for (int j = 0; j < 4; ++j) Of[j][r] *= sc;
      }
    }
    #pragma unroll
    for (int r = 0; r < 4; ++r) {
      float p[4], rs = 0.0f;
      #pragma unroll
      for (int j = 0; j < 4; ++j) { p[j] = __expf(sv[r][j] - m_i[r]); rs += p[j]; }
      rs += __shfl_xor(rs, 1);
      rs += __shfl_xor(rs, 2);
      rs += __shfl_xor(rs, 4);
      rs += __shfl_xor(rs, 8);
      l_i[r] += rs;
      #pragma unroll
      for (int j = 0; j < 4; ++j) {
        const int prow = fq*4 + r;
        const int idx = prow*80 + j*16 + fr;
        Ps[wave][idx ^ ((prow>>2)<<4)] = f2b(p[j]);
      }
    }

    // O += P V   (Ps is per-wave: lgkmcnt ordering suffices, no barrier)
    __builtin_amdgcn_s_setprio(1);
    #pragma unroll
    for (int kc = 0; kc < 2; ++kc) {
      const int pidx = fr*80 + kc*32 + fq*8;
      const bf16x8 pa = *(const bf16x8*)&Ps[wave][pidx ^ ((fr>>2)<<4)];
      #pragma unroll
      for (int j = 0; j < 4; ++j) {
        const int vrow = j*16 + fr;
        const bf16x8 bV = *(const bf16x8*)&Vs[cur][vrow*64 + (((kc*4 + fq) ^ (vrow & 7))*8)];
        Of[j] = __builtin_amdgcn_mfma_f32_16x16x32_bf16(pa, bV, Of[j], 0, 0, 0);
      }
    }
    __builtin_amdgcn_s_setprio(0);
    __syncthreads();   // drains prefetch vmcnt + protects LDS buffers
  }

  // epilogue: O[q][d] -> o[mbg][t][hh*64+d]
  #pragma unroll
  for (int r = 0; r < 4; ++r) {
    const float inv = 1.0f / l_i[r];
    ushort* op = o + ((size_t)mbg*T_ + (qrow_abs0 + r))*D_ + hh*DK_ + fr;
    #pragma unroll
    for (int j = 0; j < 4; ++j)
      op[j*16] = f2b(Of[j][r] * inv);
  }
}

extern "C" void kernel_launch(void* const* d_in, const int* in_sizes, int n_in,
                              void* d_out, int out_size, void* d_ws, size_t ws_size,
                              hipStream_t stream)
{
  const int*   x       = (const int*)  d_in[0];
  const float* tok_emb = (const float*)d_in[1];
  const float* pos_emb = (const float*)d_in[2];
  const float* ln1_w   = (const float*)d_in[3];
  const float* ln1_b   = (const float*)d_in[4];
  const float* qkv_w   = (const float*)d_in[5];
  const float* qkv_b   = (const float*)d_in[6];
  const float* out_w   = (const float*)d_in[7];
  const float* out_b   = (const float*)d_in[8];
  const float* ln2_w   = (const float*)d_in[9];
  const float* ln2_b   = (const float*)d_in[10];
  const float* ff1_w   = (const float*)d_in[11];
  const float* ff1_b   = (const float*)d_in[12];
  const float* ff2_w   = (const float*)d_in[13];
  const float* ff2_b   = (const float*)d_in[14];
  const float* lnf_w   = (const float*)d_in[15];
  const float* lnf_b   = (const float*)d_in[16];
  const float* head_w  = (const float*)d_in[17];
  const float* head_b  = (const float*)d_in[18];
  float* outp = (float*)d_out;

  const size_t HS = (size_t)M_*B_*T_*D_;            // 4,194,304
  float*  h     = (float*)d_ws;                     // 16.78 MB
  ushort* nb    = (ushort*)(h + HS);                // 8.39 MB
  ushort* qkvb  = nb + HS;                          // 12.58M ushorts
  ushort* ob    = qkvb + (size_t)M_*B_*T_*3*D_;     // 4.19M ushorts
  ushort* fb    = qkvb;                             // overlay (16.78M ushorts)
  ushort* vtb   = ob + HS;                          // 4.19M ushorts
  ushort* wslot = vtb + HS;                         // 4.19M ushorts

  const int ROWS = M_*B_*T_;
  const int NQ = M_*3*D_*D_/8, NO = M_*D_*D_/8, NF = M_*FF_*D_/8, NH = M_*V_*D_/8;

  k_embed<<<dim3(T_, B_, M_), 128, 0, stream>>>(x, tok_emb, pos_emb, h);

  for (int l = 0; l < L_; ++l) {
    k_ln<<<ROWS, 256, 0, stream>>>(h, ln1_w + l*M_*D_, ln1_b + l*M_*D_, nb);

    k_cvt<<<NQ/256, 256, 0, stream>>>(qkv_w + (size_t)l*M_*3*D_*D_, wslot, NQ);
    k_gemm<1,0,0,0,1><<<dim3(BT_/128, (3*D_)/128, M_), 256, 0, stream>>>(
        nb, wslot, qkv_b + l*M_*3*D_, nullptr, qkvb, vtb, BT_, 3*D_, D_);

    k_attn_mfma<<<dim3(T_/64, H_, M_*B_), 256, 0, stream>>>(qkvb, vtb, ob);

    k_cvt<<<NO/256, 256, 0, stream>>>(out_w + (size_t)l*M_*D_*D_, wslot, NO);
    k_gemm<0,0,1,0,0><<<dim3(BT_/128, D_/128, M_), 256, 0, stream>>>(
        ob, wslot, out_b + l*M_*D_, h, h, nullptr, BT_, D_, D_);

    k_ln<<<ROWS, 256, 0, stream>>>(h, ln2_w + l*M_*D_, ln2_b + l*M_*D_, nb);

    k_cvt<<<NF/256, 256, 0, stream>>>(ff1_w + (size_t)l*M_*FF_*D_, wslot, NF);
    k_gemm<1,1,0,0,0><<<dim3(BT_/128, FF_/128, M_), 256, 0, stream>>>(
        nb, wslot, ff1_b + l*M_*FF_, nullptr, fb, nullptr, BT_, FF_, D_);

    k_cvt<<<NF/256, 256, 0, stream>>>(ff2_w + (size_t)l*M_*D_*FF_, wslot, NF);
    k_gemm<0,0,1,0,0><<<dim3(BT_/128, D_/128, M_), 256, 0, stream>>>(
        fb, wslot, ff2_b + l*M_*D_, h, h, nullptr, BT_, D_, FF_);
  }

  k_ln<<<ROWS, 256, 0, stream>>>(h, lnf_w, lnf_b, nb);
  k_cvt<<<NH/256, 256, 0, stream>>>(head_w, wslot, NH);
  k_gemm<0,0,0,1,0><<<dim3(BT_/128, V_/128, M_), 256, 0, stream>>>(
      nb, wslot, head_b, nullptr, outp, nullptr, BT_, V_, D_);
}

// Round 5
// 758.066 us; speedup vs baseline: 5.4600x; 1.1904x over previous
//
#include <hip/hip_runtime.h>

#define M_  4
#define B_  2
#define T_  1024
#define D_  512
#define V_  128
#define L_  4
#define H_  8
#define FF_ 2048
#define DK_ 64
#define BT_ (B_*T_)
#define EPS_ 1e-5f

typedef __attribute__((ext_vector_type(8))) short  bf16x8;
typedef __attribute__((ext_vector_type(4))) float  f32x4;
typedef __attribute__((ext_vector_type(8))) ushort ushort8v;

__device__ __forceinline__ float b2f(ushort u) {
  union { unsigned int i; float f; } c; c.i = ((unsigned int)u) << 16; return c.f;
}
__device__ __forceinline__ ushort f2b(float f) {
  union { float f; unsigned int i; } c; c.f = f;
  return (ushort)((c.i + 0x7FFFu + ((c.i >> 16) & 1u)) >> 16);
}
__device__ __forceinline__ void gload_lds16(const void* g, void* l) {
  __builtin_amdgcn_global_load_lds((const __attribute__((address_space(1))) unsigned int*)g,
                                   (__attribute__((address_space(3))) unsigned int*)l, 16, 0, 0);
}

// ---------------- embedding ----------------
__global__ __launch_bounds__(128)
void k_embed(const int* __restrict__ x, const float* __restrict__ tok,
             const float* __restrict__ pos, float* __restrict__ h)
{
  const int t = blockIdx.x, b = blockIdx.y, m = blockIdx.z;
  const int d = threadIdx.x * 4;
  const int xv = x[b*T_ + t];
  const float4 tv = *(const float4*)&tok[((size_t)m*V_ + xv)*D_ + d];
  const float4 pv = *(const float4*)&pos[((size_t)m*1024 + t)*D_ + d];
  float4 r;
  r.x = tv.x + pv.x; r.y = tv.y + pv.y; r.z = tv.z + pv.z; r.w = tv.w + pv.w;
  *(float4*)&h[(((size_t)m*B_ + b)*T_ + t)*D_ + d] = r;
}

// ---------------- fused per-layer weight convert (4 segments, one launch) ----------------
#define NQ8_ 393216
#define NO8_ 131072
#define NF8_ 524288
__global__ __launch_bounds__(256)
void k_cvt4(const float* __restrict__ s0, const float* __restrict__ s1,
            const float* __restrict__ s2, const float* __restrict__ s3,
            ushort* __restrict__ d0, ushort* __restrict__ d1,
            ushort* __restrict__ d2, ushort* __restrict__ d3)
{
  int i = blockIdx.x * 256 + threadIdx.x;
  const float* s; ushort* d;
  if (i < NQ8_)                    { s = s0; d = d0; }
  else if (i < NQ8_+NO8_)          { s = s1; d = d1; i -= NQ8_; }
  else if (i < NQ8_+NO8_+NF8_)     { s = s2; d = d2; i -= NQ8_+NO8_; }
  else                             { s = s3; d = d3; i -= NQ8_+NO8_+NF8_; }
  const float4 a = ((const float4*)s)[i*2];
  const float4 b = ((const float4*)s)[i*2+1];
  ushort8v o;
  o[0]=f2b(a.x); o[1]=f2b(a.y); o[2]=f2b(a.z); o[3]=f2b(a.w);
  o[4]=f2b(b.x); o[5]=f2b(b.y); o[6]=f2b(b.z); o[7]=f2b(b.w);
  ((ushort8v*)d)[i] = o;
}

__global__ __launch_bounds__(256)
void k_cvt(const float* __restrict__ src, ushort* __restrict__ dst, int n8)
{
  const int i = blockIdx.x * 256 + threadIdx.x;
  if (i >= n8) return;
  const float4 a = ((const float4*)src)[i*2];
  const float4 b = ((const float4*)src)[i*2+1];
  ushort8v o;
  o[0]=f2b(a.x); o[1]=f2b(a.y); o[2]=f2b(a.z); o[3]=f2b(a.w);
  o[4]=f2b(b.x); o[5]=f2b(b.y); o[6]=f2b(b.z); o[7]=f2b(b.w);
  ((ushort8v*)dst)[i] = o;
}

// ---------------- layernorm: one WAVE per row (D=512 = 64 lanes x 8) ----------------
__global__ __launch_bounds__(256)
void k_ln(const float* __restrict__ x, const float* __restrict__ w,
          const float* __restrict__ bb, ushort* __restrict__ y)
{
  const int row  = blockIdx.x * 4 + (threadIdx.x >> 6);
  const int lane = threadIdx.x & 63;
  const int m = row >> 11;                 // row / BT_
  const float* xp = x + (size_t)row*D_ + lane*8;
  const float4 v0 = *(const float4*)xp;
  const float4 v1 = *(const float4*)(xp + 4);
  float s  = v0.x+v0.y+v0.z+v0.w + v1.x+v1.y+v1.z+v1.w;
  float s2 = v0.x*v0.x+v0.y*v0.y+v0.z*v0.z+v0.w*v0.w
           + v1.x*v1.x+v1.y*v1.y+v1.z*v1.z+v1.w*v1.w;
  #pragma unroll
  for (int off = 1; off < 64; off <<= 1) {
    s  += __shfl_xor(s, off);
    s2 += __shfl_xor(s2, off);
  }
  const float mu   = s * (1.0f/D_);
  const float var  = s2 * (1.0f/D_) - mu*mu;
  const float rstd = rsqrtf(var + EPS_);
  const float* wp = w + m*D_ + lane*8;
  const float* bp = bb + m*D_ + lane*8;
  const float4 w0 = *(const float4*)wp, w1 = *(const float4*)(wp+4);
  const float4 b0 = *(const float4*)bp, b1 = *(const float4*)(bp+4);
  ushort8v o;
  o[0]=f2b((v0.x-mu)*rstd*w0.x+b0.x); o[1]=f2b((v0.y-mu)*rstd*w0.y+b0.y);
  o[2]=f2b((v0.z-mu)*rstd*w0.z+b0.z); o[3]=f2b((v0.w-mu)*rstd*w0.w+b0.w);
  o[4]=f2b((v1.x-mu)*rstd*w1.x+b1.x); o[5]=f2b((v1.y-mu)*rstd*w1.y+b1.y);
  o[6]=f2b((v1.z-mu)*rstd*w1.z+b1.z); o[7]=f2b((v1.w-mu)*rstd*w1.w+b1.w);
  *(ushort8v*)&y[(size_t)row*D_ + lane*8] = o;
}

// ---------------- MFMA GEMM: 128x128 tile, BK=64, swizzled LDS ----------------
template<int OUTBF, int ACT, int RES, int HEADOUT, int SPLITV>
__global__ __launch_bounds__(256)
void k_gemm(const ushort* __restrict__ A, const ushort* __restrict__ W,
            const float* __restrict__ bias, const float* __restrict__ resid,
            void* __restrict__ C, ushort* __restrict__ vt, int RR, int NN, int KK)
{
  const int m  = blockIdx.z;
  const int r0 = blockIdx.x * 128;
  const int c0 = blockIdx.y * 128;
  const ushort* Am = A + (size_t)m*RR*KK;
  const ushort* Wm = W + (size_t)m*NN*KK;

  __shared__ ushort As[128*64];
  __shared__ ushort Bs[128*64];

  const int tid  = threadIdx.x;
  const int lane = tid & 63;
  const int wave = tid >> 6;
  const int wr = wave >> 1, wc = wave & 1;
  const int fr = lane & 15;
  const int fq = lane >> 4;

  f32x4 acc[4][4];
  #pragma unroll
  for (int i = 0; i < 4; ++i)
    #pragma unroll
    for (int j = 0; j < 4; ++j)
      acc[i][j] = (f32x4){0.f,0.f,0.f,0.f};

  for (int k0 = 0; k0 < KK; k0 += 64) {
    #pragma unroll
    for (int i = 0; i < 4; ++i) {
      const int c = i*256 + tid;
      const int row = c >> 3, ch = c & 7;
      const int sch = ch ^ (row & 7);
      gload_lds16(Am + (size_t)(r0+row)*KK + k0 + sch*8, (ushort*)As + (size_t)c*8);
      gload_lds16(Wm + (size_t)(c0+row)*KK + k0 + sch*8, (ushort*)Bs + (size_t)c*8);
    }
    __syncthreads();

    #pragma unroll
    for (int kk = 0; kk < 2; ++kk) {
      bf16x8 af[4], bfv[4];
      #pragma unroll
      for (int i = 0; i < 4; ++i) {
        const int rowA = wr*64 + i*16 + fr;
        af[i]  = *(const bf16x8*)&As[rowA*64 + (((kk*4 + fq) ^ (rowA & 7))*8)];
        const int rowB = wc*64 + i*16 + fr;
        bfv[i] = *(const bf16x8*)&Bs[rowB*64 + (((kk*4 + fq) ^ (rowB & 7))*8)];
      }
      #pragma unroll
      for (int i = 0; i < 4; ++i)
        #pragma unroll
        for (int j = 0; j < 4; ++j)
          acc[i][j] = __builtin_amdgcn_mfma_f32_16x16x32_bf16(af[i], bfv[j], acc[i][j], 0, 0, 0);
    }
    __syncthreads();
  }

  const int colb = c0 + wc*64 + fr;
  float bi[4];
  #pragma unroll
  for (int j = 0; j < 4; ++j) bi[j] = bias[(size_t)m*NN + colb + j*16];

  #pragma unroll
  for (int i = 0; i < 4; ++i) {
    #pragma unroll
    for (int r = 0; r < 4; ++r) {
      const int row = r0 + wr*64 + i*16 + fq*4 + r;
      #pragma unroll
      for (int j = 0; j < 4; ++j) {
        float val = acc[i][j][r] + bi[j];
        if (ACT) val = fmaxf(val, 0.0f);
        const int col = colb + j*16;
        if (SPLITV) {
          const int hh2 = col / 192;
          const int sub = col - hh2*192;
          if (sub >= 128) {
            const int mbg = m*B_ + (row >> 10);
            const int t = row & 1023;
            vt[(((size_t)mbg*8 + hh2)*64 + (sub-128))*1024 + t] = f2b(val);
          } else {
            ((ushort*)C)[((size_t)m*RR + row)*NN + col] = f2b(val);
          }
        } else {
          size_t oidx;
          if (HEADOUT) {
            const int b = row >> 10, t = row & 1023;
            oidx = (((size_t)b*M_ + m)*T_ + t)*V_ + col;
          } else {
            oidx = ((size_t)m*RR + row)*NN + col;
          }
          float v2 = val;
          if (RES) v2 += resid[oidx];
          if (OUTBF) ((ushort*)C)[oidx] = f2b(v2);
          else       ((float*)C)[oidx]  = v2;
        }
      }
    }
  }
}

// ---------------- MFMA flash attention, 2-phase pipelined, triangle-balanced ----------------
// block p handles q-tiles {p, 15-p}: every block does exactly 17 K-tile steps.
__global__ __launch_bounds__(256)
void k_attn_mfma(const ushort* __restrict__ qkvb, const ushort* __restrict__ vt,
                 ushort* __restrict__ o)
{
  const int pair = blockIdx.x;   // 0..7
  const int hh   = blockIdx.y;
  const int mbg  = blockIdx.z;

  __shared__ ushort Qs[64*64];
  __shared__ ushort Ks[2][64*64];
  __shared__ ushort Vs[2][64*64];
  __shared__ ushort Ps[4][16*80];

  const int tid  = threadIdx.x;
  const int lane = tid & 63;
  const int wave = tid >> 6;
  const int fr = lane & 15;
  const int fq = lane >> 4;

  const ushort* qk_base = qkvb + (size_t)mbg*T_*(3*D_) + hh*(3*DK_);
  const ushort* vt_base = vt + ((size_t)(mbg*8 + hh)*64)*1024;

  #pragma unroll 1
  for (int pass = 0; pass < 2; ++pass) {
    const int qb = pass ? (15 - pair) : pair;

    // stage Q + K/V tile 0
    #pragma unroll
    for (int i = 0; i < 2; ++i) {
      const int c = wave*128 + i*64 + lane;
      const int row = c >> 3, ch = c & 7;
      const int sch = (ch ^ (row & 7)) * 8;
      gload_lds16(qk_base + (size_t)(qb*64 + row)*(3*D_) + sch,
                  (ushort*)Qs + (size_t)(wave*128 + i*64)*8);
      gload_lds16(qk_base + (size_t)row*(3*D_) + DK_ + sch,
                  (ushort*)Ks[0] + (size_t)(wave*128 + i*64)*8);
      gload_lds16(vt_base + (size_t)row*1024 + sch,
                  (ushort*)Vs[0] + (size_t)(wave*128 + i*64)*8);
    }
    __syncthreads();

    bf16x8 aQ[2];
    #pragma unroll
    for (int kc = 0; kc < 2; ++kc) {
      const int qrow = wave*16 + fr;
      aQ[kc] = *(const bf16x8*)&Qs[qrow*64 + (((kc*4 + fq) ^ (qrow & 7))*8)];
    }

    float m_i[4], l_i[4];
    f32x4 Of[4];
    #pragma unroll
    for (int r = 0; r < 4; ++r) { m_i[r] = -3.0e38f; l_i[r] = 0.0f; }
    #pragma unroll
    for (int j = 0; j < 4; ++j) Of[j] = (f32x4){0.f,0.f,0.f,0.f};

    const int qrow_abs0 = qb*64 + wave*16 + fq*4;

    for (int kb = 0; kb <= qb; ++kb) {
      const int cur = kb & 1;

      if (kb < qb) {
        #pragma unroll
        for (int i = 0; i < 2; ++i) {
          const int c = wave*128 + i*64 + lane;
          const int row = c >> 3, ch = c & 7;
          const int sch = (ch ^ (row & 7)) * 8;
          gload_lds16(qk_base + (size_t)((kb+1)*64 + row)*(3*D_) + DK_ + sch,
                      (ushort*)Ks[cur^1] + (size_t)(wave*128 + i*64)*8);
          gload_lds16(vt_base + (size_t)row*1024 + (kb+1)*64 + sch,
                      (ushort*)Vs[cur^1] + (size_t)(wave*128 + i*64)*8);
        }
      }

      f32x4 acc[4];
      #pragma unroll
      for (int j = 0; j < 4; ++j) acc[j] = (f32x4){0.f,0.f,0.f,0.f};
      __builtin_amdgcn_s_setprio(1);
      #pragma unroll
      for (int kc = 0; kc < 2; ++kc) {
        #pragma unroll
        for (int j = 0; j < 4; ++j) {
          const int krow = j*16 + fr;
          const bf16x8 bK = *(const bf16x8*)&Ks[cur][krow*64 + (((kc*4 + fq) ^ (krow & 7))*8)];
          acc[j] = __builtin_amdgcn_mfma_f32_16x16x32_bf16(aQ[kc], bK, acc[j], 0, 0, 0);
        }
      }
      __builtin_amdgcn_s_setprio(0);

      // online softmax with defer-max (THR=8)
      float sv[4][4], rm4[4];
      float ex = -3.0e38f;
      #pragma unroll
      for (int r = 0; r < 4; ++r) {
        #pragma unroll
        for (int j = 0; j < 4; ++j) {
          sv[r][j] = acc[j][r] * 0.125f;
          if (kb == qb && (kb*64 + j*16 + fr) > (qrow_abs0 + r)) sv[r][j] = -3.0e38f;
        }
        float rm = fmaxf(fmaxf(sv[r][0], sv[r][1]), fmaxf(sv[r][2], sv[r][3]));
        rm = fmaxf(rm, __shfl_xor(rm, 1));
        rm = fmaxf(rm, __shfl_xor(rm, 2));
        rm = fmaxf(rm, __shfl_xor(rm, 4));
        rm = fmaxf(rm, __shfl_xor(rm, 8));
        rm4[r] = rm;
        ex = fmaxf(ex, rm - m_i[r]);
      }
      if (!__all(ex <= 8.0f)) {
        #pragma unroll
        for (int r = 0; r < 4; ++r) {
          const float mn = fmaxf(m_i[r], rm4[r]);
          const float sc = __expf(m_i[r] - mn);
          m_i[r] = mn;
          l_i[r] *= sc;
          #pragma unroll
          for (int j = 0; j < 4; ++j) Of[j][r] *= sc;
        }
      }
      #pragma unroll
      for (int r = 0; r < 4; ++r) {
        float p[4], rs = 0.0f;
        #pragma unroll
        for (int j = 0; j < 4; ++j) { p[j] = __expf(sv[r][j] - m_i[r]); rs += p[j]; }
        rs += __shfl_xor(rs, 1);
        rs += __shfl_xor(rs, 2);
        rs += __shfl_xor(rs, 4);
        rs += __shfl_xor(rs, 8);
        l_i[r] += rs;
        #pragma unroll
        for (int j = 0; j < 4; ++j) {
          const int prow = fq*4 + r;
          const int idx = prow*80 + j*16 + fr;
          Ps[wave][idx ^ ((prow>>2)<<4)] = f2b(p[j]);
        }
      }

      __builtin_amdgcn_s_setprio(1);
      #pragma unroll
      for (int kc = 0; kc < 2; ++kc) {
        const int pidx = fr*80 + kc*32 + fq*8;
        const bf16x8 pa = *(const bf16x8*)&Ps[wave][pidx ^ ((fr>>2)<<4)];
        #pragma unroll
        for (int j = 0; j < 4; ++j) {
          const int vrow = j*16 + fr;
          const bf16x8 bV = *(const bf16x8*)&Vs[cur][vrow*64 + (((kc*4 + fq) ^ (vrow & 7))*8)];
          Of[j] = __builtin_amdgcn_mfma_f32_16x16x32_bf16(pa, bV, Of[j], 0, 0, 0);
        }
      }
      __builtin_amdgcn_s_setprio(0);
      __syncthreads();
    }

    #pragma unroll
    for (int r = 0; r < 4; ++r) {
      const float inv = 1.0f / l_i[r];
      ushort* op = o + ((size_t)mbg*T_ + (qrow_abs0 + r))*D_ + hh*DK_ + fr;
      #pragma unroll
      for (int j = 0; j < 4; ++j)
        op[j*16] = f2b(Of[j][r] * inv);
    }
  }
}

extern "C" void kernel_launch(void* const* d_in, const int* in_sizes, int n_in,
                              void* d_out, int out_size, void* d_ws, size_t ws_size,
                              hipStream_t stream)
{
  const int*   x       = (const int*)  d_in[0];
  const float* tok_emb = (const float*)d_in[1];
  const float* pos_emb = (const float*)d_in[2];
  const float* ln1_w   = (const float*)d_in[3];
  const float* ln1_b   = (const float*)d_in[4];
  const float* qkv_w   = (const float*)d_in[5];
  const float* qkv_b   = (const float*)d_in[6];
  const float* out_w   = (const float*)d_in[7];
  const float* out_b   = (const float*)d_in[8];
  const float* ln2_w   = (const float*)d_in[9];
  const float* ln2_b   = (const float*)d_in[10];
  const float* ff1_w   = (const float*)d_in[11];
  const float* ff1_b   = (const float*)d_in[12];
  const float* ff2_w   = (const float*)d_in[13];
  const float* ff2_b   = (const float*)d_in[14];
  const float* lnf_w   = (const float*)d_in[15];
  const float* lnf_b   = (const float*)d_in[16];
  const float* head_w  = (const float*)d_in[17];
  const float* head_b  = (const float*)d_in[18];
  float* outp = (float*)d_out;

  const size_t HS = (size_t)M_*B_*T_*D_;            // 4,194,304
  float*  h     = (float*)d_ws;                     // 16.78 MB
  ushort* nb    = (ushort*)(h + HS);                // 8.39 MB
  ushort* qkvb  = nb + HS;                          // 12.58M ushorts
  ushort* ob    = qkvb + (size_t)M_*B_*T_*3*D_;     // 4.19M ushorts
  ushort* fb    = qkvb;                             // overlay
  ushort* vtb   = ob + HS;                          // 4.19M ushorts
  ushort* wq    = vtb + HS;                         // weight slots (25.2 MB total)
  ushort* wo    = wq  + (size_t)M_*3*D_*D_;
  ushort* wf1   = wo  + (size_t)M_*D_*D_;
  ushort* wf2   = wf1 + (size_t)M_*FF_*D_;

  const int ROWS = M_*B_*T_;
  const int NH = M_*V_*D_/8;
  const int CVT4_BLK = (NQ8_ + NO8_ + NF8_ + NF8_) / 256;   // 6144

  k_embed<<<dim3(T_, B_, M_), 128, 0, stream>>>(x, tok_emb, pos_emb, h);

  for (int l = 0; l < L_; ++l) {
    k_cvt4<<<CVT4_BLK, 256, 0, stream>>>(
        qkv_w + (size_t)l*M_*3*D_*D_, out_w + (size_t)l*M_*D_*D_,
        ff1_w + (size_t)l*M_*FF_*D_,  ff2_w + (size_t)l*M_*D_*FF_,
        wq, wo, wf1, wf2);

    k_ln<<<ROWS/4, 256, 0, stream>>>(h, ln1_w + l*M_*D_, ln1_b + l*M_*D_, nb);

    k_gemm<1,0,0,0,1><<<dim3(BT_/128, (3*D_)/128, M_), 256, 0, stream>>>(
        nb, wq, qkv_b + l*M_*3*D_, nullptr, qkvb, vtb, BT_, 3*D_, D_);

    k_attn_mfma<<<dim3(T_/128, H_, M_*B_), 256, 0, stream>>>(qkvb, vtb, ob);

    k_gemm<0,0,1,0,0><<<dim3(BT_/128, D_/128, M_), 256, 0, stream>>>(
        ob, wo, out_b + l*M_*D_, h, h, nullptr, BT_, D_, D_);

    k_ln<<<ROWS/4, 256, 0, stream>>>(h, ln2_w + l*M_*D_, ln2_b + l*M_*D_, nb);

    k_gemm<1,1,0,0,0><<<dim3(BT_/128, FF_/128, M_), 256, 0, stream>>>(
        nb, wf1, ff1_b + l*M_*FF_, nullptr, fb, nullptr, BT_, FF_, D_);

    k_gemm<0,0,1,0,0><<<dim3(BT_/128, D_/128, M_), 256, 0, stream>>>(
        fb, wf2, ff2_b + l*M_*D_, h, h, nullptr, BT_, D_, FF_);
  }

  k_ln<<<ROWS/4, 256, 0, stream>>>(h, lnf_w, lnf_b, nb);
  k_cvt<<<NH/256, 256, 0, stream>>>(head_w, wq, NH);
  k_gemm<0,0,0,1,0><<<dim3(BT_/128, V_/128, M_), 256, 0, stream>>>(
      nb, wq, head_b, nullptr, outp, nullptr, BT_, V_, D_);
}

// Round 6
// 665.415 us; speedup vs baseline: 6.2203x; 1.1392x over previous
//
#include <hip/hip_runtime.h>

#define M_  4
#define B_  2
#define T_  1024
#define D_  512
#define V_  128
#define L_  4
#define H_  8
#define FF_ 2048
#define DK_ 64
#define BT_ (B_*T_)
#define EPS_ 1e-5f

typedef __attribute__((ext_vector_type(8))) short  bf16x8;
typedef __attribute__((ext_vector_type(4))) float  f32x4;
typedef __attribute__((ext_vector_type(8))) ushort ushort8v;

__device__ __forceinline__ float b2f(ushort u) {
  union { unsigned int i; float f; } c; c.i = ((unsigned int)u) << 16; return c.f;
}
__device__ __forceinline__ ushort f2b(float f) {
  union { float f; unsigned int i; } c; c.f = f;
  return (ushort)((c.i + 0x7FFFu + ((c.i >> 16) & 1u)) >> 16);
}
__device__ __forceinline__ void gload_lds16(const void* g, void* l) {
  __builtin_amdgcn_global_load_lds((const __attribute__((address_space(1))) unsigned int*)g,
                                   (__attribute__((address_space(3))) unsigned int*)l, 16, 0, 0);
}

// ---------------- embedding ----------------
__global__ __launch_bounds__(128)
void k_embed(const int* __restrict__ x, const float* __restrict__ tok,
             const float* __restrict__ pos, float* __restrict__ h)
{
  const int t = blockIdx.x, b = blockIdx.y, m = blockIdx.z;
  const int d = threadIdx.x * 4;
  const int xv = x[b*T_ + t];
  const float4 tv = *(const float4*)&tok[((size_t)m*V_ + xv)*D_ + d];
  const float4 pv = *(const float4*)&pos[((size_t)m*1024 + t)*D_ + d];
  float4 r;
  r.x = tv.x + pv.x; r.y = tv.y + pv.y; r.z = tv.z + pv.z; r.w = tv.w + pv.w;
  *(float4*)&h[(((size_t)m*B_ + b)*T_ + t)*D_ + d] = r;
}

// ---------------- fused per-layer weight convert (4 segments, one launch) ----------------
#define NQ8_ 393216
#define NO8_ 131072
#define NF8_ 524288
__global__ __launch_bounds__(256)
void k_cvt4(const float* __restrict__ s0, const float* __restrict__ s1,
            const float* __restrict__ s2, const float* __restrict__ s3,
            ushort* __restrict__ d0, ushort* __restrict__ d1,
            ushort* __restrict__ d2, ushort* __restrict__ d3)
{
  int i = blockIdx.x * 256 + threadIdx.x;
  const float* s; ushort* d;
  if (i < NQ8_)                    { s = s0; d = d0; }
  else if (i < NQ8_+NO8_)          { s = s1; d = d1; i -= NQ8_; }
  else if (i < NQ8_+NO8_+NF8_)     { s = s2; d = d2; i -= NQ8_+NO8_; }
  else                             { s = s3; d = d3; i -= NQ8_+NO8_+NF8_; }
  const float4 a = ((const float4*)s)[i*2];
  const float4 b = ((const float4*)s)[i*2+1];
  ushort8v o;
  o[0]=f2b(a.x); o[1]=f2b(a.y); o[2]=f2b(a.z); o[3]=f2b(a.w);
  o[4]=f2b(b.x); o[5]=f2b(b.y); o[6]=f2b(b.z); o[7]=f2b(b.w);
  ((ushort8v*)d)[i] = o;
}

__global__ __launch_bounds__(256)
void k_cvt(const float* __restrict__ src, ushort* __restrict__ dst, int n8)
{
  const int i = blockIdx.x * 256 + threadIdx.x;
  if (i >= n8) return;
  const float4 a = ((const float4*)src)[i*2];
  const float4 b = ((const float4*)src)[i*2+1];
  ushort8v o;
  o[0]=f2b(a.x); o[1]=f2b(a.y); o[2]=f2b(a.z); o[3]=f2b(a.w);
  o[4]=f2b(b.x); o[5]=f2b(b.y); o[6]=f2b(b.z); o[7]=f2b(b.w);
  ((ushort8v*)dst)[i] = o;
}

// ---------------- layernorm: one WAVE per row (D=512 = 64 lanes x 8) ----------------
__global__ __launch_bounds__(256)
void k_ln(const float* __restrict__ x, const float* __restrict__ w,
          const float* __restrict__ bb, ushort* __restrict__ y)
{
  const int row  = blockIdx.x * 4 + (threadIdx.x >> 6);
  const int lane = threadIdx.x & 63;
  const int m = row >> 11;                 // row / BT_
  const float* xp = x + (size_t)row*D_ + lane*8;
  const float4 v0 = *(const float4*)xp;
  const float4 v1 = *(const float4*)(xp + 4);
  float s  = v0.x+v0.y+v0.z+v0.w + v1.x+v1.y+v1.z+v1.w;
  float s2 = v0.x*v0.x+v0.y*v0.y+v0.z*v0.z+v0.w*v0.w
           + v1.x*v1.x+v1.y*v1.y+v1.z*v1.z+v1.w*v1.w;
  #pragma unroll
  for (int off = 1; off < 64; off <<= 1) {
    s  += __shfl_xor(s, off);
    s2 += __shfl_xor(s2, off);
  }
  const float mu   = s * (1.0f/D_);
  const float var  = s2 * (1.0f/D_) - mu*mu;
  const float rstd = rsqrtf(var + EPS_);
  const float* wp = w + m*D_ + lane*8;
  const float* bp = bb + m*D_ + lane*8;
  const float4 w0 = *(const float4*)wp, w1 = *(const float4*)(wp+4);
  const float4 b0 = *(const float4*)bp, b1 = *(const float4*)(bp+4);
  ushort8v o;
  o[0]=f2b((v0.x-mu)*rstd*w0.x+b0.x); o[1]=f2b((v0.y-mu)*rstd*w0.y+b0.y);
  o[2]=f2b((v0.z-mu)*rstd*w0.z+b0.z); o[3]=f2b((v0.w-mu)*rstd*w0.w+b0.w);
  o[4]=f2b((v1.x-mu)*rstd*w1.x+b1.x); o[5]=f2b((v1.y-mu)*rstd*w1.y+b1.y);
  o[6]=f2b((v1.z-mu)*rstd*w1.z+b1.z); o[7]=f2b((v1.w-mu)*rstd*w1.w+b1.w);
  *(ushort8v*)&y[(size_t)row*D_ + lane*8] = o;
}

// ---------------- MFMA GEMM: 128x128 tile, BK=64, swizzled LDS, 2-phase dbuf ----------------
template<int OUTBF, int ACT, int RES, int HEADOUT, int SPLITV>
__global__ __launch_bounds__(256)
void k_gemm(const ushort* __restrict__ A, const ushort* __restrict__ W,
            const float* __restrict__ bias, const float* __restrict__ resid,
            void* __restrict__ C, ushort* __restrict__ vt, int RR, int NN, int KK)
{
  const int m  = blockIdx.z;
  const int r0 = blockIdx.x * 128;
  const int c0 = blockIdx.y * 128;
  const ushort* Am = A + (size_t)m*RR*KK;
  const ushort* Wm = W + (size_t)m*NN*KK;

  __shared__ ushort As[2][128*64];
  __shared__ ushort Bs[2][128*64];

  const int tid  = threadIdx.x;
  const int lane = tid & 63;
  const int wave = tid >> 6;
  const int wr = wave >> 1, wc = wave & 1;
  const int fr = lane & 15;
  const int fq = lane >> 4;

  f32x4 acc[4][4];
  #pragma unroll
  for (int i = 0; i < 4; ++i)
    #pragma unroll
    for (int j = 0; j < 4; ++j)
      acc[i][j] = (f32x4){0.f,0.f,0.f,0.f};

  // stage K-tile 0 into buf 0
  #pragma unroll
  for (int i = 0; i < 4; ++i) {
    const int c = i*256 + tid;
    const int row = c >> 3, ch = c & 7;
    const int sch = ch ^ (row & 7);
    gload_lds16(Am + (size_t)(r0+row)*KK + sch*8, (ushort*)As[0] + (size_t)c*8);
    gload_lds16(Wm + (size_t)(c0+row)*KK + sch*8, (ushort*)Bs[0] + (size_t)c*8);
  }
  __syncthreads();

  const int NK = KK >> 6;
  for (int kt = 0; kt < NK; ++kt) {
    const int cur = kt & 1;

    // prefetch next K-tile into the other buffer; its completion is enforced
    // by this iteration's ending barrier (vmcnt(0) drain), while the MFMA
    // below runs with the loads in flight.
    if (kt + 1 < NK) {
      const int k0 = (kt + 1) * 64;
      #pragma unroll
      for (int i = 0; i < 4; ++i) {
        const int c = i*256 + tid;
        const int row = c >> 3, ch = c & 7;
        const int sch = ch ^ (row & 7);
        gload_lds16(Am + (size_t)(r0+row)*KK + k0 + sch*8, (ushort*)As[cur^1] + (size_t)c*8);
        gload_lds16(Wm + (size_t)(c0+row)*KK + k0 + sch*8, (ushort*)Bs[cur^1] + (size_t)c*8);
      }
    }

    #pragma unroll
    for (int kk = 0; kk < 2; ++kk) {
      bf16x8 af[4], bfv[4];
      #pragma unroll
      for (int i = 0; i < 4; ++i) {
        const int rowA = wr*64 + i*16 + fr;
        af[i]  = *(const bf16x8*)&As[cur][rowA*64 + (((kk*4 + fq) ^ (rowA & 7))*8)];
        const int rowB = wc*64 + i*16 + fr;
        bfv[i] = *(const bf16x8*)&Bs[cur][rowB*64 + (((kk*4 + fq) ^ (rowB & 7))*8)];
      }
      #pragma unroll
      for (int i = 0; i < 4; ++i)
        #pragma unroll
        for (int j = 0; j < 4; ++j)
          acc[i][j] = __builtin_amdgcn_mfma_f32_16x16x32_bf16(af[i], bfv[j], acc[i][j], 0, 0, 0);
    }
    __syncthreads();
  }

  const int colb = c0 + wc*64 + fr;
  float bi[4];
  #pragma unroll
  for (int j = 0; j < 4; ++j) bi[j] = bias[(size_t)m*NN + colb + j*16];

  #pragma unroll
  for (int i = 0; i < 4; ++i) {
    #pragma unroll
    for (int r = 0; r < 4; ++r) {
      const int row = r0 + wr*64 + i*16 + fq*4 + r;
      #pragma unroll
      for (int j = 0; j < 4; ++j) {
        float val = acc[i][j][r] + bi[j];
        if (ACT) val = fmaxf(val, 0.0f);
        const int col = colb + j*16;
        if (SPLITV) {
          const int hh2 = col / 192;
          const int sub = col - hh2*192;
          if (sub >= 128) {
            const int mbg = m*B_ + (row >> 10);
            const int t = row & 1023;
            vt[(((size_t)mbg*8 + hh2)*64 + (sub-128))*1024 + t] = f2b(val);
          } else {
            ((ushort*)C)[((size_t)m*RR + row)*NN + col] = f2b(val);
          }
        } else {
          size_t oidx;
          if (HEADOUT) {
            const int b = row >> 10, t = row & 1023;
            oidx = (((size_t)b*M_ + m)*T_ + t)*V_ + col;
          } else {
            oidx = ((size_t)m*RR + row)*NN + col;
          }
          float v2 = val;
          if (RES) v2 += resid[oidx];
          if (OUTBF) ((ushort*)C)[oidx] = f2b(v2);
          else       ((float*)C)[oidx]  = v2;
        }
      }
    }
  }
}

// ---------------- MFMA flash attention, 2-phase pipelined, triangle-balanced ----------------
__global__ __launch_bounds__(256)
void k_attn_mfma(const ushort* __restrict__ qkvb, const ushort* __restrict__ vt,
                 ushort* __restrict__ o)
{
  const int pair = blockIdx.x;   // 0..7
  const int hh   = blockIdx.y;
  const int mbg  = blockIdx.z;

  __shared__ ushort Qs[64*64];
  __shared__ ushort Ks[2][64*64];
  __shared__ ushort Vs[2][64*64];
  __shared__ ushort Ps[4][16*80];

  const int tid  = threadIdx.x;
  const int lane = tid & 63;
  const int wave = tid >> 6;
  const int fr = lane & 15;
  const int fq = lane >> 4;

  const ushort* qk_base = qkvb + (size_t)mbg*T_*(3*D_) + hh*(3*DK_);
  const ushort* vt_base = vt + ((size_t)(mbg*8 + hh)*64)*1024;

  #pragma unroll 1
  for (int pass = 0; pass < 2; ++pass) {
    const int qb = pass ? (15 - pair) : pair;

    #pragma unroll
    for (int i = 0; i < 2; ++i) {
      const int c = wave*128 + i*64 + lane;
      const int row = c >> 3, ch = c & 7;
      const int sch = (ch ^ (row & 7)) * 8;
      gload_lds16(qk_base + (size_t)(qb*64 + row)*(3*D_) + sch,
                  (ushort*)Qs + (size_t)(wave*128 + i*64)*8);
      gload_lds16(qk_base + (size_t)row*(3*D_) + DK_ + sch,
                  (ushort*)Ks[0] + (size_t)(wave*128 + i*64)*8);
      gload_lds16(vt_base + (size_t)row*1024 + sch,
                  (ushort*)Vs[0] + (size_t)(wave*128 + i*64)*8);
    }
    __syncthreads();

    bf16x8 aQ[2];
    #pragma unroll
    for (int kc = 0; kc < 2; ++kc) {
      const int qrow = wave*16 + fr;
      aQ[kc] = *(const bf16x8*)&Qs[qrow*64 + (((kc*4 + fq) ^ (qrow & 7))*8)];
    }

    float m_i[4], l_i[4];
    f32x4 Of[4];
    #pragma unroll
    for (int r = 0; r < 4; ++r) { m_i[r] = -3.0e38f; l_i[r] = 0.0f; }
    #pragma unroll
    for (int j = 0; j < 4; ++j) Of[j] = (f32x4){0.f,0.f,0.f,0.f};

    const int qrow_abs0 = qb*64 + wave*16 + fq*4;

    for (int kb = 0; kb <= qb; ++kb) {
      const int cur = kb & 1;

      if (kb < qb) {
        #pragma unroll
        for (int i = 0; i < 2; ++i) {
          const int c = wave*128 + i*64 + lane;
          const int row = c >> 3, ch = c & 7;
          const int sch = (ch ^ (row & 7)) * 8;
          gload_lds16(qk_base + (size_t)((kb+1)*64 + row)*(3*D_) + DK_ + sch,
                      (ushort*)Ks[cur^1] + (size_t)(wave*128 + i*64)*8);
          gload_lds16(vt_base + (size_t)row*1024 + (kb+1)*64 + sch,
                      (ushort*)Vs[cur^1] + (size_t)(wave*128 + i*64)*8);
        }
      }

      f32x4 acc[4];
      #pragma unroll
      for (int j = 0; j < 4; ++j) acc[j] = (f32x4){0.f,0.f,0.f,0.f};
      __builtin_amdgcn_s_setprio(1);
      #pragma unroll
      for (int kc = 0; kc < 2; ++kc) {
        #pragma unroll
        for (int j = 0; j < 4; ++j) {
          const int krow = j*16 + fr;
          const bf16x8 bK = *(const bf16x8*)&Ks[cur][krow*64 + (((kc*4 + fq) ^ (krow & 7))*8)];
          acc[j] = __builtin_amdgcn_mfma_f32_16x16x32_bf16(aQ[kc], bK, acc[j], 0, 0, 0);
        }
      }
      __builtin_amdgcn_s_setprio(0);

      float sv[4][4], rm4[4];
      float ex = -3.0e38f;
      #pragma unroll
      for (int r = 0; r < 4; ++r) {
        #pragma unroll
        for (int j = 0; j < 4; ++j) {
          sv[r][j] = acc[j][r] * 0.125f;
          if (kb == qb && (kb*64 + j*16 + fr) > (qrow_abs0 + r)) sv[r][j] = -3.0e38f;
        }
        float rm = fmaxf(fmaxf(sv[r][0], sv[r][1]), fmaxf(sv[r][2], sv[r][3]));
        rm = fmaxf(rm, __shfl_xor(rm, 1));
        rm = fmaxf(rm, __shfl_xor(rm, 2));
        rm = fmaxf(rm, __shfl_xor(rm, 4));
        rm = fmaxf(rm, __shfl_xor(rm, 8));
        rm4[r] = rm;
        ex = fmaxf(ex, rm - m_i[r]);
      }
      if (!__all(ex <= 8.0f)) {
        #pragma unroll
        for (int r = 0; r < 4; ++r) {
          const float mn = fmaxf(m_i[r], rm4[r]);
          const float sc = __expf(m_i[r] - mn);
          m_i[r] = mn;
          l_i[r] *= sc;
          #pragma unroll
          for (int j = 0; j < 4; ++j) Of[j][r] *= sc;
        }
      }
      #pragma unroll
      for (int r = 0; r < 4; ++r) {
        float p[4], rs = 0.0f;
        #pragma unroll
        for (int j = 0; j < 4; ++j) { p[j] = __expf(sv[r][j] - m_i[r]); rs += p[j]; }
        rs += __shfl_xor(rs, 1);
        rs += __shfl_xor(rs, 2);
        rs += __shfl_xor(rs, 4);
        rs += __shfl_xor(rs, 8);
        l_i[r] += rs;
        #pragma unroll
        for (int j = 0; j < 4; ++j) {
          const int prow = fq*4 + r;
          const int idx = prow*80 + j*16 + fr;
          Ps[wave][idx ^ ((prow>>2)<<4)] = f2b(p[j]);
        }
      }

      __builtin_amdgcn_s_setprio(1);
      #pragma unroll
      for (int kc = 0; kc < 2; ++kc) {
        const int pidx = fr*80 + kc*32 + fq*8;
        const bf16x8 pa = *(const bf16x8*)&Ps[wave][pidx ^ ((fr>>2)<<4)];
        #pragma unroll
        for (int j = 0; j < 4; ++j) {
          const int vrow = j*16 + fr;
          const bf16x8 bV = *(const bf16x8*)&Vs[cur][vrow*64 + (((kc*4 + fq) ^ (vrow & 7))*8)];
          Of[j] = __builtin_amdgcn_mfma_f32_16x16x32_bf16(pa, bV, Of[j], 0, 0, 0);
        }
      }
      __builtin_amdgcn_s_setprio(0);
      __syncthreads();
    }

    #pragma unroll
    for (int r = 0; r < 4; ++r) {
      const float inv = 1.0f / l_i[r];
      ushort* op = o + ((size_t)mbg*T_ + (qrow_abs0 + r))*D_ + hh*DK_ + fr;
      #pragma unroll
      for (int j = 0; j < 4; ++j)
        op[j*16] = f2b(Of[j][r] * inv);
    }
  }
}

extern "C" void kernel_launch(void* const* d_in, const int* in_sizes, int n_in,
                              void* d_out, int out_size, void* d_ws, size_t ws_size,
                              hipStream_t stream)
{
  const int*   x       = (const int*)  d_in[0];
  const float* tok_emb = (const float*)d_in[1];
  const float* pos_emb = (const float*)d_in[2];
  const float* ln1_w   = (const float*)d_in[3];
  const float* ln1_b   = (const float*)d_in[4];
  const float* qkv_w   = (const float*)d_in[5];
  const float* qkv_b   = (const float*)d_in[6];
  const float* out_w   = (const float*)d_in[7];
  const float* out_b   = (const float*)d_in[8];
  const float* ln2_w   = (const float*)d_in[9];
  const float* ln2_b   = (const float*)d_in[10];
  const float* ff1_w   = (const float*)d_in[11];
  const float* ff1_b   = (const float*)d_in[12];
  const float* ff2_w   = (const float*)d_in[13];
  const float* ff2_b   = (const float*)d_in[14];
  const float* lnf_w   = (const float*)d_in[15];
  const float* lnf_b   = (const float*)d_in[16];
  const float* head_w  = (const float*)d_in[17];
  const float* head_b  = (const float*)d_in[18];
  float* outp = (float*)d_out;

  const size_t HS = (size_t)M_*B_*T_*D_;            // 4,194,304
  float*  h     = (float*)d_ws;                     // 16.78 MB
  ushort* nb    = (ushort*)(h + HS);                // 8.39 MB
  ushort* qkvb  = nb + HS;                          // 12.58M ushorts
  ushort* ob    = qkvb + (size_t)M_*B_*T_*3*D_;     // 4.19M ushorts
  ushort* fb    = qkvb;                             // overlay
  ushort* vtb   = ob + HS;                          // 4.19M ushorts
  ushort* wq    = vtb + HS;                         // weight slots (25.2 MB total)
  ushort* wo    = wq  + (size_t)M_*3*D_*D_;
  ushort* wf1   = wo  + (size_t)M_*D_*D_;
  ushort* wf2   = wf1 + (size_t)M_*FF_*D_;

  const int ROWS = M_*B_*T_;
  const int NH = M_*V_*D_/8;
  const int CVT4_BLK = (NQ8_ + NO8_ + NF8_ + NF8_) / 256;   // 6144

  k_embed<<<dim3(T_, B_, M_), 128, 0, stream>>>(x, tok_emb, pos_emb, h);

  for (int l = 0; l < L_; ++l) {
    k_cvt4<<<CVT4_BLK, 256, 0, stream>>>(
        qkv_w + (size_t)l*M_*3*D_*D_, out_w + (size_t)l*M_*D_*D_,
        ff1_w + (size_t)l*M_*FF_*D_,  ff2_w + (size_t)l*M_*D_*FF_,
        wq, wo, wf1, wf2);

    k_ln<<<ROWS/4, 256, 0, stream>>>(h, ln1_w + l*M_*D_, ln1_b + l*M_*D_, nb);

    k_gemm<1,0,0,0,1><<<dim3(BT_/128, (3*D_)/128, M_), 256, 0, stream>>>(
        nb, wq, qkv_b + l*M_*3*D_, nullptr, qkvb, vtb, BT_, 3*D_, D_);

    k_attn_mfma<<<dim3(T_/128, H_, M_*B_), 256, 0, stream>>>(qkvb, vtb, ob);

    k_gemm<0,0,1,0,0><<<dim3(BT_/128, D_/128, M_), 256, 0, stream>>>(
        ob, wo, out_b + l*M_*D_, h, h, nullptr, BT_, D_, D_);

    k_ln<<<ROWS/4, 256, 0, stream>>>(h, ln2_w + l*M_*D_, ln2_b + l*M_*D_, nb);

    k_gemm<1,1,0,0,0><<<dim3(BT_/128, FF_/128, M_), 256, 0, stream>>>(
        nb, wf1, ff1_b + l*M_*FF_, nullptr, fb, nullptr, BT_, FF_, D_);

    k_gemm<0,0,1,0,0><<<dim3(BT_/128, D_/128, M_), 256, 0, stream>>>(
        fb, wf2, ff2_b + l*M_*D_, h, h, nullptr, BT_, D_, FF_);
  }

  k_ln<<<ROWS/4, 256, 0, stream>>>(h, lnf_w, lnf_b, nb);
  k_cvt<<<NH/256, 256, 0, stream>>>(head_w, wq, NH);
  k_gemm<0,0,0,1,0><<<dim3(BT_/128, V_/128, M_), 256, 0, stream>>>(
      nb, wq, head_b, nullptr, outp, nullptr, BT_, V_, D_);
}

// Round 7
// 651.977 us; speedup vs baseline: 6.3485x; 1.0206x over previous
//
#include <hip/hip_runtime.h>

#define M_  4
#define B_  2
#define T_  1024
#define D_  512
#define V_  128
#define L_  4
#define H_  8
#define FF_ 2048
#define DK_ 64
#define BT_ (B_*T_)
#define EPS_ 1e-5f

typedef __attribute__((ext_vector_type(8))) short  bf16x8;
typedef __attribute__((ext_vector_type(4))) float  f32x4;
typedef __attribute__((ext_vector_type(8))) ushort ushort8v;

__device__ __forceinline__ float b2f(ushort u) {
  union { unsigned int i; float f; } c; c.i = ((unsigned int)u) << 16; return c.f;
}
__device__ __forceinline__ ushort f2b(float f) {
  union { float f; unsigned int i; } c; c.f = f;
  return (ushort)((c.i + 0x7FFFu + ((c.i >> 16) & 1u)) >> 16);
}
__device__ __forceinline__ void gload_lds16(const void* g, void* l) {
  __builtin_amdgcn_global_load_lds((const __attribute__((address_space(1))) unsigned int*)g,
                                   (__attribute__((address_space(3))) unsigned int*)l, 16, 0, 0);
}

// ---------------- embedding ----------------
__global__ __launch_bounds__(128)
void k_embed(const int* __restrict__ x, const float* __restrict__ tok,
             const float* __restrict__ pos, float* __restrict__ h)
{
  const int t = blockIdx.x, b = blockIdx.y, m = blockIdx.z;
  const int d = threadIdx.x * 4;
  const int xv = x[b*T_ + t];
  const float4 tv = *(const float4*)&tok[((size_t)m*V_ + xv)*D_ + d];
  const float4 pv = *(const float4*)&pos[((size_t)m*1024 + t)*D_ + d];
  float4 r;
  r.x = tv.x + pv.x; r.y = tv.y + pv.y; r.z = tv.z + pv.z; r.w = tv.w + pv.w;
  *(float4*)&h[(((size_t)m*B_ + b)*T_ + t)*D_ + d] = r;
}

// ---------------- fused per-layer weight convert (4 segments, one launch) ----------------
#define NQ8_ 393216
#define NO8_ 131072
#define NF8_ 524288
__global__ __launch_bounds__(256)
void k_cvt4(const float* __restrict__ s0, const float* __restrict__ s1,
            const float* __restrict__ s2, const float* __restrict__ s3,
            ushort* __restrict__ d0, ushort* __restrict__ d1,
            ushort* __restrict__ d2, ushort* __restrict__ d3)
{
  int i = blockIdx.x * 256 + threadIdx.x;
  const float* s; ushort* d;
  if (i < NQ8_)                    { s = s0; d = d0; }
  else if (i < NQ8_+NO8_)          { s = s1; d = d1; i -= NQ8_; }
  else if (i < NQ8_+NO8_+NF8_)     { s = s2; d = d2; i -= NQ8_+NO8_; }
  else                             { s = s3; d = d3; i -= NQ8_+NO8_+NF8_; }
  const float4 a = ((const float4*)s)[i*2];
  const float4 b = ((const float4*)s)[i*2+1];
  ushort8v o;
  o[0]=f2b(a.x); o[1]=f2b(a.y); o[2]=f2b(a.z); o[3]=f2b(a.w);
  o[4]=f2b(b.x); o[5]=f2b(b.y); o[6]=f2b(b.z); o[7]=f2b(b.w);
  ((ushort8v*)d)[i] = o;
}

__global__ __launch_bounds__(256)
void k_cvt(const float* __restrict__ src, ushort* __restrict__ dst, int n8)
{
  const int i = blockIdx.x * 256 + threadIdx.x;
  if (i >= n8) return;
  const float4 a = ((const float4*)src)[i*2];
  const float4 b = ((const float4*)src)[i*2+1];
  ushort8v o;
  o[0]=f2b(a.x); o[1]=f2b(a.y); o[2]=f2b(a.z); o[3]=f2b(a.w);
  o[4]=f2b(b.x); o[5]=f2b(b.y); o[6]=f2b(b.z); o[7]=f2b(b.w);
  ((ushort8v*)dst)[i] = o;
}

// ---------------- layernorm: one WAVE per row (D=512 = 64 lanes x 8) ----------------
__global__ __launch_bounds__(256)
void k_ln(const float* __restrict__ x, const float* __restrict__ w,
          const float* __restrict__ bb, ushort* __restrict__ y)
{
  const int row  = blockIdx.x * 4 + (threadIdx.x >> 6);
  const int lane = threadIdx.x & 63;
  const int m = row >> 11;                 // row / BT_
  const float* xp = x + (size_t)row*D_ + lane*8;
  const float4 v0 = *(const float4*)xp;
  const float4 v1 = *(const float4*)(xp + 4);
  float s  = v0.x+v0.y+v0.z+v0.w + v1.x+v1.y+v1.z+v1.w;
  float s2 = v0.x*v0.x+v0.y*v0.y+v0.z*v0.z+v0.w*v0.w
           + v1.x*v1.x+v1.y*v1.y+v1.z*v1.z+v1.w*v1.w;
  #pragma unroll
  for (int off = 1; off < 64; off <<= 1) {
    s  += __shfl_xor(s, off);
    s2 += __shfl_xor(s2, off);
  }
  const float mu   = s * (1.0f/D_);
  const float var  = s2 * (1.0f/D_) - mu*mu;
  const float rstd = rsqrtf(var + EPS_);
  const float* wp = w + m*D_ + lane*8;
  const float* bp = bb + m*D_ + lane*8;
  const float4 w0 = *(const float4*)wp, w1 = *(const float4*)(wp+4);
  const float4 b0 = *(const float4*)bp, b1 = *(const float4*)(bp+4);
  ushort8v o;
  o[0]=f2b((v0.x-mu)*rstd*w0.x+b0.x); o[1]=f2b((v0.y-mu)*rstd*w0.y+b0.y);
  o[2]=f2b((v0.z-mu)*rstd*w0.z+b0.z); o[3]=f2b((v0.w-mu)*rstd*w0.w+b0.w);
  o[4]=f2b((v1.x-mu)*rstd*w1.x+b1.x); o[5]=f2b((v1.y-mu)*rstd*w1.y+b1.y);
  o[6]=f2b((v1.z-mu)*rstd*w1.z+b1.z); o[7]=f2b((v1.w-mu)*rstd*w1.w+b1.w);
  *(ushort8v*)&y[(size_t)row*D_ + lane*8] = o;
}

// ---------------- MFMA GEMM: 128x128, BK=64, swizzled LDS, dbuf + counted vmcnt ----------------
template<int OUTBF, int ACT, int RES, int HEADOUT, int SPLITV>
__global__ __launch_bounds__(256)
void k_gemm(const ushort* __restrict__ A, const ushort* __restrict__ W,
            const float* __restrict__ bias, const float* __restrict__ resid,
            void* __restrict__ C, ushort* __restrict__ vt, int RR, int NN, int KK)
{
  const int m  = blockIdx.z;
  const int r0 = blockIdx.x * 128;
  const int c0 = blockIdx.y * 128;
  const ushort* Am = A + (size_t)m*RR*KK;
  const ushort* Wm = W + (size_t)m*NN*KK;

  __shared__ ushort As[2][128*64];
  __shared__ ushort Bs[2][128*64];

  const int tid  = threadIdx.x;
  const int lane = tid & 63;
  const int wave = tid >> 6;
  const int wr = wave >> 1, wc = wave & 1;
  const int fr = lane & 15;
  const int fq = lane >> 4;

  f32x4 acc[4][4];
  #pragma unroll
  for (int i = 0; i < 4; ++i)
    #pragma unroll
    for (int j = 0; j < 4; ++j)
      acc[i][j] = (f32x4){0.f,0.f,0.f,0.f};

  // stage K-tile 0 into buf 0 (8 gload_lds per wave), full drain once
  #pragma unroll
  for (int i = 0; i < 4; ++i) {
    const int c = i*256 + tid;
    const int row = c >> 3, ch = c & 7;
    const int sch = ch ^ (row & 7);
    gload_lds16(Am + (size_t)(r0+row)*KK + sch*8, (ushort*)As[0] + (size_t)c*8);
    gload_lds16(Wm + (size_t)(c0+row)*KK + sch*8, (ushort*)Bs[0] + (size_t)c*8);
  }
  __syncthreads();

  const int NK = KK >> 6;
  for (int kt = 0; kt < NK; ++kt) {
    const int cur = kt & 1;

    // issue prefetch for tile kt+1 (8 loads/wave), then COUNTED wait: retire
    // only tile-kt's loads; the 8 just-issued stay in flight across both
    // barriers and the MFMA phase (T4).
    if (kt + 1 < NK) {
      const int k0 = (kt + 1) * 64;
      #pragma unroll
      for (int i = 0; i < 4; ++i) {
        const int c = i*256 + tid;
        const int row = c >> 3, ch = c & 7;
        const int sch = ch ^ (row & 7);
        gload_lds16(Am + (size_t)(r0+row)*KK + k0 + sch*8, (ushort*)As[cur^1] + (size_t)c*8);
        gload_lds16(Wm + (size_t)(c0+row)*KK + k0 + sch*8, (ushort*)Bs[cur^1] + (size_t)c*8);
      }
      asm volatile("s_waitcnt vmcnt(8)" ::: "memory");
    } else {
      asm volatile("s_waitcnt vmcnt(0)" ::: "memory");
    }
    __builtin_amdgcn_sched_barrier(0);
    __builtin_amdgcn_s_barrier();          // B1: buf[cur] fully staged for all waves

    #pragma unroll
    for (int kk = 0; kk < 2; ++kk) {
      bf16x8 af[4], bfv[4];
      #pragma unroll
      for (int i = 0; i < 4; ++i) {
        const int rowA = wr*64 + i*16 + fr;
        af[i]  = *(const bf16x8*)&As[cur][rowA*64 + (((kk*4 + fq) ^ (rowA & 7))*8)];
        const int rowB = wc*64 + i*16 + fr;
        bfv[i] = *(const bf16x8*)&Bs[cur][rowB*64 + (((kk*4 + fq) ^ (rowB & 7))*8)];
      }
      #pragma unroll
      for (int i = 0; i < 4; ++i)
        #pragma unroll
        for (int j = 0; j < 4; ++j)
          acc[i][j] = __builtin_amdgcn_mfma_f32_16x16x32_bf16(af[i], bfv[j], acc[i][j], 0, 0, 0);
    }
    __builtin_amdgcn_s_barrier();          // B2: all reads of buf[cur] done
  }

  const int colb = c0 + wc*64 + fr;
  float bi[4];
  #pragma unroll
  for (int j = 0; j < 4; ++j) bi[j] = bias[(size_t)m*NN + colb + j*16];

  #pragma unroll
  for (int i = 0; i < 4; ++i) {
    #pragma unroll
    for (int r = 0; r < 4; ++r) {
      const int row = r0 + wr*64 + i*16 + fq*4 + r;
      #pragma unroll
      for (int j = 0; j < 4; ++j) {
        float val = acc[i][j][r] + bi[j];
        if (ACT) val = fmaxf(val, 0.0f);
        const int col = colb + j*16;
        if (SPLITV) {
          const int hh2 = col / 192;
          const int sub = col - hh2*192;
          if (sub >= 128) {
            const int mbg = m*B_ + (row >> 10);
            const int t = row & 1023;
            vt[(((size_t)mbg*8 + hh2)*64 + (sub-128))*1024 + t] = f2b(val);
          } else {
            ((ushort*)C)[((size_t)m*RR + row)*NN + col] = f2b(val);
          }
        } else {
          size_t oidx;
          if (HEADOUT) {
            const int b = row >> 10, t = row & 1023;
            oidx = (((size_t)b*M_ + m)*T_ + t)*V_ + col;
          } else {
            oidx = ((size_t)m*RR + row)*NN + col;
          }
          float v2 = val;
          if (RES) v2 += resid[oidx];
          if (OUTBF) ((ushort*)C)[oidx] = f2b(v2);
          else       ((float*)C)[oidx]  = v2;
        }
      }
    }
  }
}

// ---------------- MFMA flash attention, dbuf + counted vmcnt, triangle-balanced ----------------
__global__ __launch_bounds__(256)
void k_attn_mfma(const ushort* __restrict__ qkvb, const ushort* __restrict__ vt,
                 ushort* __restrict__ o)
{
  const int pair = blockIdx.x;   // 0..7
  const int hh   = blockIdx.y;
  const int mbg  = blockIdx.z;

  __shared__ ushort Qs[64*64];
  __shared__ ushort Ks[2][64*64];
  __shared__ ushort Vs[2][64*64];
  __shared__ ushort Ps[4][16*80];

  const int tid  = threadIdx.x;
  const int lane = tid & 63;
  const int wave = tid >> 6;
  const int fr = lane & 15;
  const int fq = lane >> 4;

  const ushort* qk_base = qkvb + (size_t)mbg*T_*(3*D_) + hh*(3*DK_);
  const ushort* vt_base = vt + ((size_t)(mbg*8 + hh)*64)*1024;

  #pragma unroll 1
  for (int pass = 0; pass < 2; ++pass) {
    const int qb = pass ? (15 - pair) : pair;

    // stage Q + K/V tile 0 (6 loads/wave), full drain once per pass
    #pragma unroll
    for (int i = 0; i < 2; ++i) {
      const int c = wave*128 + i*64 + lane;
      const int row = c >> 3, ch = c & 7;
      const int sch = (ch ^ (row & 7)) * 8;
      gload_lds16(qk_base + (size_t)(qb*64 + row)*(3*D_) + sch,
                  (ushort*)Qs + (size_t)(wave*128 + i*64)*8);
      gload_lds16(qk_base + (size_t)row*(3*D_) + DK_ + sch,
                  (ushort*)Ks[0] + (size_t)(wave*128 + i*64)*8);
      gload_lds16(vt_base + (size_t)row*1024 + sch,
                  (ushort*)Vs[0] + (size_t)(wave*128 + i*64)*8);
    }
    __syncthreads();

    bf16x8 aQ[2];
    #pragma unroll
    for (int kc = 0; kc < 2; ++kc) {
      const int qrow = wave*16 + fr;
      aQ[kc] = *(const bf16x8*)&Qs[qrow*64 + (((kc*4 + fq) ^ (qrow & 7))*8)];
    }

    float m_i[4], l_i[4];
    f32x4 Of[4];
    #pragma unroll
    for (int r = 0; r < 4; ++r) { m_i[r] = -3.0e38f; l_i[r] = 0.0f; }
    #pragma unroll
    for (int j = 0; j < 4; ++j) Of[j] = (f32x4){0.f,0.f,0.f,0.f};

    const int qrow_abs0 = qb*64 + wave*16 + fq*4;

    for (int kb = 0; kb <= qb; ++kb) {
      const int cur = kb & 1;

      // issue prefetch (4 loads/wave), counted wait retires only tile-kb loads
      if (kb < qb) {
        #pragma unroll
        for (int i = 0; i < 2; ++i) {
          const int c = wave*128 + i*64 + lane;
          const int row = c >> 3, ch = c & 7;
          const int sch = (ch ^ (row & 7)) * 8;
          gload_lds16(qk_base + (size_t)((kb+1)*64 + row)*(3*D_) + DK_ + sch,
                      (ushort*)Ks[cur^1] + (size_t)(wave*128 + i*64)*8);
          gload_lds16(vt_base + (size_t)row*1024 + (kb+1)*64 + sch,
                      (ushort*)Vs[cur^1] + (size_t)(wave*128 + i*64)*8);
        }
        asm volatile("s_waitcnt vmcnt(4)" ::: "memory");
      } else {
        asm volatile("s_waitcnt vmcnt(0)" ::: "memory");
      }
      __builtin_amdgcn_sched_barrier(0);
      __builtin_amdgcn_s_barrier();        // B1: Ks/Vs[cur] staged

      f32x4 acc[4];
      #pragma unroll
      for (int j = 0; j < 4; ++j) acc[j] = (f32x4){0.f,0.f,0.f,0.f};
      __builtin_amdgcn_s_setprio(1);
      #pragma unroll
      for (int kc = 0; kc < 2; ++kc) {
        #pragma unroll
        for (int j = 0; j < 4; ++j) {
          const int krow = j*16 + fr;
          const bf16x8 bK = *(const bf16x8*)&Ks[cur][krow*64 + (((kc*4 + fq) ^ (krow & 7))*8)];
          acc[j] = __builtin_amdgcn_mfma_f32_16x16x32_bf16(aQ[kc], bK, acc[j], 0, 0, 0);
        }
      }
      __builtin_amdgcn_s_setprio(0);

      float sv[4][4], rm4[4];
      float ex = -3.0e38f;
      #pragma unroll
      for (int r = 0; r < 4; ++r) {
        #pragma unroll
        for (int j = 0; j < 4; ++j) {
          sv[r][j] = acc[j][r] * 0.125f;
          if (kb == qb && (kb*64 + j*16 + fr) > (qrow_abs0 + r)) sv[r][j] = -3.0e38f;
        }
        float rm = fmaxf(fmaxf(sv[r][0], sv[r][1]), fmaxf(sv[r][2], sv[r][3]));
        rm = fmaxf(rm, __shfl_xor(rm, 1));
        rm = fmaxf(rm, __shfl_xor(rm, 2));
        rm = fmaxf(rm, __shfl_xor(rm, 4));
        rm = fmaxf(rm, __shfl_xor(rm, 8));
        rm4[r] = rm;
        ex = fmaxf(ex, rm - m_i[r]);
      }
      if (!__all(ex <= 8.0f)) {
        #pragma unroll
        for (int r = 0; r < 4; ++r) {
          const float mn = fmaxf(m_i[r], rm4[r]);
          const float sc = __expf(m_i[r] - mn);
          m_i[r] = mn;
          l_i[r] *= sc;
          #pragma unroll
          for (int j = 0; j < 4; ++j) Of[j][r] *= sc;
        }
      }
      #pragma unroll
      for (int r = 0; r < 4; ++r) {
        float p[4], rs = 0.0f;
        #pragma unroll
        for (int j = 0; j < 4; ++j) { p[j] = __expf(sv[r][j] - m_i[r]); rs += p[j]; }
        rs += __shfl_xor(rs, 1);
        rs += __shfl_xor(rs, 2);
        rs += __shfl_xor(rs, 4);
        rs += __shfl_xor(rs, 8);
        l_i[r] += rs;
        #pragma unroll
        for (int j = 0; j < 4; ++j) {
          const int prow = fq*4 + r;
          const int idx = prow*80 + j*16 + fr;
          Ps[wave][idx ^ ((prow>>2)<<4)] = f2b(p[j]);
        }
      }

      __builtin_amdgcn_s_setprio(1);
      #pragma unroll
      for (int kc = 0; kc < 2; ++kc) {
        const int pidx = fr*80 + kc*32 + fq*8;
        const bf16x8 pa = *(const bf16x8*)&Ps[wave][pidx ^ ((fr>>2)<<4)];
        #pragma unroll
        for (int j = 0; j < 4; ++j) {
          const int vrow = j*16 + fr;
          const bf16x8 bV = *(const bf16x8*)&Vs[cur][vrow*64 + (((kc*4 + fq) ^ (vrow & 7))*8)];
          Of[j] = __builtin_amdgcn_mfma_f32_16x16x32_bf16(pa, bV, Of[j], 0, 0, 0);
        }
      }
      __builtin_amdgcn_s_setprio(0);
      __builtin_amdgcn_s_barrier();        // B2: all reads of buf[cur] done
    }

    #pragma unroll
    for (int r = 0; r < 4; ++r) {
      const float inv = 1.0f / l_i[r];
      ushort* op = o + ((size_t)mbg*T_ + (qrow_abs0 + r))*D_ + hh*DK_ + fr;
      #pragma unroll
      for (int j = 0; j < 4; ++j)
        op[j*16] = f2b(Of[j][r] * inv);
    }
  }
}

extern "C" void kernel_launch(void* const* d_in, const int* in_sizes, int n_in,
                              void* d_out, int out_size, void* d_ws, size_t ws_size,
                              hipStream_t stream)
{
  const int*   x       = (const int*)  d_in[0];
  const float* tok_emb = (const float*)d_in[1];
  const float* pos_emb = (const float*)d_in[2];
  const float* ln1_w   = (const float*)d_in[3];
  const float* ln1_b   = (const float*)d_in[4];
  const float* qkv_w   = (const float*)d_in[5];
  const float* qkv_b   = (const float*)d_in[6];
  const float* out_w   = (const float*)d_in[7];
  const float* out_b   = (const float*)d_in[8];
  const float* ln2_w   = (const float*)d_in[9];
  const float* ln2_b   = (const float*)d_in[10];
  const float* ff1_w   = (const float*)d_in[11];
  const float* ff1_b   = (const float*)d_in[12];
  const float* ff2_w   = (const float*)d_in[13];
  const float* ff2_b   = (const float*)d_in[14];
  const float* lnf_w   = (const float*)d_in[15];
  const float* lnf_b   = (const float*)d_in[16];
  const float* head_w  = (const float*)d_in[17];
  const float* head_b  = (const float*)d_in[18];
  float* outp = (float*)d_out;

  const size_t HS = (size_t)M_*B_*T_*D_;            // 4,194,304
  float*  h     = (float*)d_ws;                     // 16.78 MB
  ushort* nb    = (ushort*)(h + HS);                // 8.39 MB
  ushort* qkvb  = nb + HS;                          // 12.58M ushorts
  ushort* ob    = qkvb + (size_t)M_*B_*T_*3*D_;     // 4.19M ushorts
  ushort* fb    = qkvb;                             // overlay
  ushort* vtb   = ob + HS;                          // 4.19M ushorts
  ushort* wq    = vtb + HS;                         // weight slots (25.2 MB total)
  ushort* wo    = wq  + (size_t)M_*3*D_*D_;
  ushort* wf1   = wo  + (size_t)M_*D_*D_;
  ushort* wf2   = wf1 + (size_t)M_*FF_*D_;

  const int ROWS = M_*B_*T_;
  const int NH = M_*V_*D_/8;
  const int CVT4_BLK = (NQ8_ + NO8_ + NF8_ + NF8_) / 256;   // 6144

  k_embed<<<dim3(T_, B_, M_), 128, 0, stream>>>(x, tok_emb, pos_emb, h);

  for (int l = 0; l < L_; ++l) {
    k_cvt4<<<CVT4_BLK, 256, 0, stream>>>(
        qkv_w + (size_t)l*M_*3*D_*D_, out_w + (size_t)l*M_*D_*D_,
        ff1_w + (size_t)l*M_*FF_*D_,  ff2_w + (size_t)l*M_*D_*FF_,
        wq, wo, wf1, wf2);

    k_ln<<<ROWS/4, 256, 0, stream>>>(h, ln1_w + l*M_*D_, ln1_b + l*M_*D_, nb);

    k_gemm<1,0,0,0,1><<<dim3(BT_/128, (3*D_)/128, M_), 256, 0, stream>>>(
        nb, wq, qkv_b + l*M_*3*D_, nullptr, qkvb, vtb, BT_, 3*D_, D_);

    k_attn_mfma<<<dim3(T_/128, H_, M_*B_), 256, 0, stream>>>(qkvb, vtb, ob);

    k_gemm<0,0,1,0,0><<<dim3(BT_/128, D_/128, M_), 256, 0, stream>>>(
        ob, wo, out_b + l*M_*D_, h, h, nullptr, BT_, D_, D_);

    k_ln<<<ROWS/4, 256, 0, stream>>>(h, ln2_w + l*M_*D_, ln2_b + l*M_*D_, nb);

    k_gemm<1,1,0,0,0><<<dim3(BT_/128, FF_/128, M_), 256, 0, stream>>>(
        nb, wf1, ff1_b + l*M_*FF_, nullptr, fb, nullptr, BT_, FF_, D_);

    k_gemm<0,0,1,0,0><<<dim3(BT_/128, D_/128, M_), 256, 0, stream>>>(
        fb, wf2, ff2_b + l*M_*D_, h, h, nullptr, BT_, D_, FF_);
  }

  k_ln<<<ROWS/4, 256, 0, stream>>>(h, lnf_w, lnf_b, nb);
  k_cvt<<<NH/256, 256, 0, stream>>>(head_w, wq, NH);
  k_gemm<0,0,0,1,0><<<dim3(BT_/128, V_/128, M_), 256, 0, stream>>>(
      nb, wq, head_b, nullptr, outp, nullptr, BT_, V_, D_);
}